// Round 1
// baseline (1237.424 us; speedup 1.0000x reference)
//
#include <hip/hip_runtime.h>
#include <stdint.h>

typedef unsigned long long u64;
typedef unsigned int u32;

#define BATCH 4
#define NANCH 230400          // 160*160*9
#define NBIN  8192            // 13-bit prefix histogram of descending key
#define KTARGET 4608          // top-K selection target (examined ~1100; 4x margin)
#define SELCAP 16384          // selection buffer cap per image
#define CPROC 4096            // candidates covered by pairwise bitmask (64 u64 words/row)
#define MAXD 1000
#define IMGW 1280.0f
#define IMGH 1280.0f

// ---- workspace layout (bytes). Total ~31.2 MB ----
#define HIST_OFF   0
#define SELCNT_OFF (BATCH*NBIN*4)                     // 131072
#define BSTAR_OFF  (SELCNT_OFF + BATCH*4)
#define TOTVAL_OFF (BSTAR_OFF + BATCH*4)
#define CTRL_BYTES (TOTVAL_OFF + BATCH*4)             // zeroed each launch
#define SCORE_OFF  131328                             // f32 [BATCH*NANCH]
#define DESC_OFF   (SCORE_OFF + BATCH*NANCH*4)        // u32 [BATCH*NANCH]
#define BOX_OFF    (DESC_OFF + BATCH*NANCH*4)         // float4 [BATCH*NANCH]
#define SELKEY_OFF (BOX_OFF + (size_t)BATCH*NANCH*16) // u64 [BATCH*SELCAP]
#define SBOX_OFF   (SELKEY_OFF + (size_t)BATCH*SELCAP*8)
#define SSCORE_OFF (SBOX_OFF + (size_t)BATCH*SELCAP*16)
#define SAREA_OFF  (SSCORE_OFF + (size_t)BATCH*SELCAP*4)
#define MASK_OFF   (SAREA_OFF + (size_t)BATCH*SELCAP*4)  // u64 [BATCH*CPROC*64]

// Decode: sigmoid score, box decode+clip, validity, sortable key, histogram.
// All rounding-sensitive ops via __f*_rn to match numpy f32 op-by-op (no contraction).
__global__ void decode_kernel(const float* __restrict__ obj,
                              const float4* __restrict__ deltas,
                              const float4* __restrict__ anchors,
                              float* __restrict__ score, u32* __restrict__ desc,
                              float4* __restrict__ boxes, u32* __restrict__ hist) {
    __shared__ u32 lh[NBIN];
    for (int i = threadIdx.x; i < NBIN; i += blockDim.x) lh[i] = 0;
    __syncthreads();
    int gid = blockIdx.x * blockDim.x + threadIdx.x;
    // N per image = 230400 = 900 blocks of 256 exactly -> no block spans 2 images
    if (gid < BATCH * NANCH) {
        float4 a = anchors[gid];
        float4 d = deltas[gid];
        float o = obj[gid];
        float w = __fsub_rn(a.z, a.x), h = __fsub_rn(a.w, a.y);
        float cx = __fadd_rn(a.x, __fmul_rn(0.5f, w));
        float cy = __fadd_rn(a.y, __fmul_rn(0.5f, h));
        float px = __fadd_rn(__fmul_rn(d.x, w), cx);
        float py = __fadd_rn(__fmul_rn(d.y, h), cy);
        float pw = __fmul_rn(expf(fminf(d.z, 4.0f)), w);
        float ph = __fmul_rn(expf(fminf(d.w, 4.0f)), h);
        float x1 = __fsub_rn(px, __fmul_rn(0.5f, pw));
        float y1 = __fsub_rn(py, __fmul_rn(0.5f, ph));
        float x2 = __fadd_rn(px, __fmul_rn(0.5f, pw));
        float y2 = __fadd_rn(py, __fmul_rn(0.5f, ph));
        x1 = fminf(fmaxf(x1, 0.0f), IMGW); x2 = fminf(fmaxf(x2, 0.0f), IMGW);
        y1 = fminf(fmaxf(y1, 0.0f), IMGH); y2 = fminf(fmaxf(y2, 0.0f), IMGH);
        bool valid = (__fsub_rn(x2, x1) >= 1.0f) && (__fsub_rn(y2, y1) >= 1.0f);
        float s = __fdiv_rn(1.0f, __fadd_rn(1.0f, expf(-o)));  // top logits are >0: same as np branch
        boxes[gid] = make_float4(x1, y1, x2, y2);
        score[gid] = s;
        // descending sortable key: score>0 so bits<0x80000000; smaller key = larger score
        u32 dsc = valid ? (0x7FFFFFFFu - __float_as_uint(s)) : 0xFFFFFFFFu;
        desc[gid] = dsc;
        if (valid) atomicAdd(&lh[dsc >> 19], 1u);   // valid bins land in [2064,4095]
    }
    __syncthreads();
    int img = (blockIdx.x * blockDim.x) / NANCH;
    for (int i = threadIdx.x; i < NBIN; i += blockDim.x) {
        u32 v = lh[i];
        if (v) atomicAdd(&hist[img * NBIN + i], v);
    }
}

// Find per-image prefix bin b* : first bin with cumulative count >= KTARGET (prefix-closed top-K).
__global__ void select_kernel(const u32* __restrict__ hist, u32* __restrict__ bstar,
                              u32* __restrict__ totval) {
    int img = blockIdx.x, t = threadIdx.x;   // 256 threads
    const u32* H = hist + img * NBIN;
    __shared__ u32 part[256], excl[256], tot;
    u32 s = 0;
    for (int b = t * 32; b < t * 32 + 32; b++) s += H[b];
    part[t] = s;
    __syncthreads();
    if (t == 0) {
        u32 run = 0;
        for (int k = 0; k < 256; k++) { excl[k] = run; run += part[k]; }
        tot = run;
        totval[img] = run;
    }
    __syncthreads();
    u32 e = excl[t];
    if (e < KTARGET && e + part[t] >= KTARGET) {
        u32 cum = e;
        for (int b = t * 32; b < t * 32 + 32; b++) {
            cum += H[b];
            if (cum >= KTARGET) { bstar[img] = (u32)b; break; }
        }
    }
    if (t == 0 && tot < KTARGET) bstar[img] = 8190u;  // take all valid (invalid are bin 8191)
}

__global__ void compact_kernel(const u32* __restrict__ desc, const u32* __restrict__ bstar,
                               u32* __restrict__ selcnt, u64* __restrict__ selkey) {
    int gid = blockIdx.x * blockDim.x + threadIdx.x;
    if (gid >= BATCH * NANCH) return;
    int img = gid / NANCH;
    u32 d = desc[gid];
    if (d == 0xFFFFFFFFu) return;
    if ((d >> 19) <= bstar[img]) {
        u32 pos = atomicAdd(&selcnt[img], 1u);
        if (pos < SELCAP)
            selkey[(size_t)img * SELCAP + pos] = ((u64)d << 32) | (u32)(gid - img * NANCH);
    }
}

// Enumeration (rank-count) sort of selected items. Keys are unique ((key<<32)|idx),
// so rank is a perfect permutation. Scatter gathers box/score/area into sorted arrays.
__global__ void ranksort_kernel(const u64* __restrict__ selkey, const u32* __restrict__ selcnt,
                                const float4* __restrict__ boxes, const float* __restrict__ score,
                                float4* __restrict__ sbox, float* __restrict__ sscore,
                                float* __restrict__ sarea) {
    int img = blockIdx.y;
    int C = min((int)selcnt[img], SELCAP);
    if ((int)(blockIdx.x * 256) >= C) return;
    int i = blockIdx.x * 256 + threadIdx.x;
    const u64* K = selkey + (size_t)img * SELCAP;
    __shared__ u64 tile[1024];
    bool act = i < C;
    u64 my = act ? K[i] : ~0ull;
    u32 rank = 0;
    for (int t0 = 0; t0 < C; t0 += 1024) {
        int cnt = min(1024, C - t0);
        __syncthreads();
        for (int j = threadIdx.x; j < cnt; j += 256) tile[j] = K[t0 + j];
        __syncthreads();
        for (int j = 0; j < cnt; j++) rank += (tile[j] < my) ? 1u : 0u;
    }
    if (act) {
        int ai = (int)(my & 0xFFFFFFFFu);
        int g = img * NANCH + ai;
        float4 bx = boxes[g];
        size_t o = (size_t)img * SELCAP + rank;
        sbox[o] = bx;
        sscore[o] = score[g];
        sarea[o] = __fmul_rn(fmaxf(__fsub_rn(bx.z, bx.x), 0.0f),
                             fmaxf(__fsub_rn(bx.w, bx.y), 0.0f));
    }
}

// Pairwise IOU>0.5 bitmask over the first min(C,CPROC) sorted candidates.
// Row i, word w: bits for columns j in [w*64, w*64+64). Formula replicates reference f32 ops.
__global__ void mask_kernel(const float4* __restrict__ sbox, const float* __restrict__ sarea,
                            const u32* __restrict__ selcnt, u64* __restrict__ mask) {
    int img = blockIdx.z;
    int C = min((int)selcnt[img], SELCAP);
    int Ce = min(C, CPROC);
    if ((int)(blockIdx.x * 256) >= Ce) return;
    int jtmax = (Ce + 63) >> 6;
    int jt0 = blockIdx.y * 8, jt1 = min(jt0 + 8, jtmax);
    if (jt0 >= jtmax) return;
    int i = blockIdx.x * 256 + threadIdx.x;
    const float4* SB = sbox + (size_t)img * SELCAP;
    const float* SA = sarea + (size_t)img * SELCAP;
    __shared__ float jx1[64], jy1[64], jx2[64], jy2[64], jar[64];
    bool act = i < Ce;
    float4 bi = make_float4(0, 0, 0, 0);
    float ai_ = 0.0f;
    if (act) { bi = SB[i]; ai_ = SA[i]; }
    u64* Mrow = mask + ((size_t)img * CPROC + (size_t)i) * 64;
    for (int jt = jt0; jt < jt1; jt++) {
        int jbase = jt << 6;
        int jcnt = min(64, Ce - jbase);
        __syncthreads();
        if (threadIdx.x < 64) {
            int l = threadIdx.x;
            if (l < jcnt) {
                float4 b = SB[jbase + l];
                jx1[l] = b.x; jy1[l] = b.y; jx2[l] = b.z; jy2[l] = b.w;
                jar[l] = SA[jbase + l];
            } else {
                jx1[l] = 0; jy1[l] = 0; jx2[l] = 0; jy2[l] = 0; jar[l] = 0;
            }
        }
        __syncthreads();
        if (act) {
            u64 bits = 0;
            for (int jl = 0; jl < jcnt; jl++) {
                float ix1 = fmaxf(bi.x, jx1[jl]);
                float iy1 = fmaxf(bi.y, jy1[jl]);
                float ix2 = fminf(bi.z, jx2[jl]);
                float iy2 = fminf(bi.w, jy2[jl]);
                float inter = __fmul_rn(fmaxf(__fsub_rn(ix2, ix1), 0.0f),
                                        fmaxf(__fsub_rn(iy2, iy1), 0.0f));
                float den = __fadd_rn(__fsub_rn(__fadd_rn(ai_, jar[jl]), inter), 1e-9f);
                if (__fdiv_rn(inter, den) > 0.5f) bits |= (1ull << jl);
            }
            Mrow[jt] = bits;
        }
    }
}

__device__ __forceinline__ bool supp_by_acc(float4 bx, float ar, int acc, int lane,
                                            const float* ax1, const float* ay1,
                                            const float* ax2, const float* ay2,
                                            const float* aar) {
    bool hit = false;
    for (int k = lane; k < acc; k += 64) {
        float ix1 = fmaxf(bx.x, ax1[k]);
        float iy1 = fmaxf(bx.y, ay1[k]);
        float ix2 = fminf(bx.z, ax2[k]);
        float iy2 = fminf(bx.w, ay2[k]);
        float inter = __fmul_rn(fmaxf(__fsub_rn(ix2, ix1), 0.0f),
                                fmaxf(__fsub_rn(iy2, iy1), 0.0f));
        float den = __fadd_rn(__fsub_rn(__fadd_rn(aar[k], ar), inter), 1e-9f);
        if (__fdiv_rn(inter, den) > 0.5f) { hit = true; break; }
    }
    return __ballot(hit) != 0ull;
}

// One wave per image. Suppressed bitset for CPROC candidates: lane l holds word l.
// Blocks of 64 candidates resolved in-register via a 64x64 mask tile (one word/lane).
__global__ void sweep_kernel(const float4* __restrict__ sbox, const float* __restrict__ sscore,
                             const float* __restrict__ sarea, const u32* __restrict__ selcnt,
                             const u32* __restrict__ totval, const u64* __restrict__ mask,
                             const u64* __restrict__ selkey, const u32* __restrict__ descarr,
                             const float4* __restrict__ boxes, const float* __restrict__ scorearr,
                             float* __restrict__ out) {
    int img = blockIdx.x, lane = threadIdx.x;  // 64 threads
    int C = min((int)selcnt[img], SELCAP);
    int Ce = min(C, CPROC);
    const float4* SB = sbox + (size_t)img * SELCAP;
    const float* SS = sscore + (size_t)img * SELCAP;
    const float* SA = sarea + (size_t)img * SELCAP;
    const u64* M = mask + (size_t)img * CPROC * 64;
    __shared__ float ax1[MAXD], ay1[MAXD], ax2[MAXD], ay2[MAXD], aar[MAXD];
    float* ob = out + (size_t)img * MAXD * 4;
    float* os = out + (size_t)BATCH * MAXD * 4 + (size_t)img * MAXD;
    float* ov = out + (size_t)BATCH * MAXD * 5 + (size_t)img * MAXD;
    u64 sup = 0;
    int acc = 0;
    int nblk = (Ce + 63) >> 6;
    for (int ib = 0; ib < nblk && acc < MAXD; ib++) {
        int base = ib << 6;
        int bcount = min(64, Ce - base);
        u64 tile = 0;
        if (lane < bcount) tile = M[(size_t)(base + lane) * 64 + ib];
        u64 ext = __shfl(sup, ib);
        u64 cur = ext, newm = 0;
        int na = 0;
        for (int b = 0; b < bcount; b++) {           // uniform across lanes
            if (acc + na >= MAXD) break;
            if (!((cur >> b) & 1ull)) {
                newm |= (1ull << b);
                na++;
                cur |= __shfl(tile, b);              // row (base+b)'s intra-block bits
            }
        }
        u64 m = newm;
        while (m) {
            int b = __builtin_ctzll(m);
            m &= (m - 1);
            int i = base + b;
            sup |= M[(size_t)i * 64 + lane];         // full-row suppression
            float4 bx = SB[i];
            if (lane == 0) {
                ob[acc * 4 + 0] = bx.x; ob[acc * 4 + 1] = bx.y;
                ob[acc * 4 + 2] = bx.z; ob[acc * 4 + 3] = bx.w;
                os[acc] = SS[i]; ov[acc] = 1.0f;
                ax1[acc] = bx.x; ay1[acc] = bx.y; ax2[acc] = bx.z; ay2[acc] = bx.w;
                aar[acc] = SA[i];
            }
            acc++;
        }
    }
    __syncthreads();
    // Continuation A (exact, rarely taken): selected candidates beyond the mask window.
    for (int i = Ce; i < C && acc < MAXD; i++) {
        float4 bx = SB[i];
        float ar = SA[i];
        if (!supp_by_acc(bx, ar, acc, lane, ax1, ay1, ax2, ay2, aar)) {
            if (lane == 0) {
                ob[acc * 4 + 0] = bx.x; ob[acc * 4 + 1] = bx.y;
                ob[acc * 4 + 2] = bx.z; ob[acc * 4 + 3] = bx.w;
                os[acc] = SS[i]; ov[acc] = 1.0f;
                ax1[acc] = bx.x; ay1[acc] = bx.y; ax2[acc] = bx.z; ay2[acc] = bx.w;
                aar[acc] = SA[i];
            }
            __syncthreads();
            acc++;
        }
    }
    // Continuation B (exact deep fallback, ~never taken): valid candidates beyond selection.
    u32 tv = totval[img];
    if (acc < MAXD && (u32)C < tv && (u32)C == selcnt[img]) {
        u64 lk = 0;
        for (int j = lane; j < C; j += 64) lk = max(lk, selkey[(size_t)img * SELCAP + j]);
        for (int off = 32; off; off >>= 1) {
            u64 o = __shfl_down(lk, off);
            lk = max(lk, o);
        }
        lk = __shfl(lk, 0);
        while (acc < MAXD) {
            u64 best = ~0ull;
            for (int j = lane; j < NANCH; j += 64) {
                u32 d = descarr[(size_t)img * NANCH + j];
                if (d != 0xFFFFFFFFu) {
                    u64 k = ((u64)d << 32) | (u32)j;
                    if (k > lk && k < best) best = k;
                }
            }
            for (int off = 32; off; off >>= 1) {
                u64 o = __shfl_down(best, off);
                best = min(best, o);
            }
            best = __shfl(best, 0);
            if (best == ~0ull) break;
            lk = best;
            int ai = (int)(best & 0xFFFFFFFFu);
            int g = img * NANCH + ai;
            float4 bx = boxes[g];
            float ar = __fmul_rn(fmaxf(__fsub_rn(bx.z, bx.x), 0.0f),
                                 fmaxf(__fsub_rn(bx.w, bx.y), 0.0f));
            if (!supp_by_acc(bx, ar, acc, lane, ax1, ay1, ax2, ay2, aar)) {
                if (lane == 0) {
                    ob[acc * 4 + 0] = bx.x; ob[acc * 4 + 1] = bx.y;
                    ob[acc * 4 + 2] = bx.z; ob[acc * 4 + 3] = bx.w;
                    os[acc] = scorearr[g]; ov[acc] = 1.0f;
                    ax1[acc] = bx.x; ay1[acc] = bx.y; ax2[acc] = bx.z; ay2[acc] = bx.w;
                    aar[acc] = ar;
                }
                __syncthreads();
                acc++;
            }
        }
    }
}

extern "C" void kernel_launch(void* const* d_in, const int* in_sizes, int n_in,
                              void* d_out, int out_size, void* d_ws, size_t ws_size,
                              hipStream_t stream) {
    const float* obj = (const float*)d_in[0];
    const float4* deltas = (const float4*)d_in[1];
    const float4* anchors = (const float4*)d_in[2];
    char* ws = (char*)d_ws;
    u32* hist = (u32*)(ws + HIST_OFF);
    u32* selcnt = (u32*)(ws + SELCNT_OFF);
    u32* bstar = (u32*)(ws + BSTAR_OFF);
    u32* totval = (u32*)(ws + TOTVAL_OFF);
    float* score = (float*)(ws + SCORE_OFF);
    u32* desc = (u32*)(ws + DESC_OFF);
    float4* boxes = (float4*)(ws + BOX_OFF);
    u64* selkey = (u64*)(ws + SELKEY_OFF);
    float4* sbox = (float4*)(ws + SBOX_OFF);
    float* sscore = (float*)(ws + SSCORE_OFF);
    float* sarea = (float*)(ws + SAREA_OFF);
    u64* mask = (u64*)(ws + MASK_OFF);
    float* out = (float*)d_out;

    hipMemsetAsync(ws + HIST_OFF, 0, CTRL_BYTES, stream);                  // hist + counters
    hipMemsetAsync(d_out, 0, (size_t)out_size * sizeof(float), stream);    // zero-padded outputs

    decode_kernel<<<3600, 256, 0, stream>>>(obj, deltas, anchors, score, desc, boxes, hist);
    select_kernel<<<BATCH, 256, 0, stream>>>(hist, bstar, totval);
    compact_kernel<<<3600, 256, 0, stream>>>(desc, bstar, selcnt, selkey);
    ranksort_kernel<<<dim3(SELCAP / 256, BATCH), 256, 0, stream>>>(selkey, selcnt, boxes, score,
                                                                   sbox, sscore, sarea);
    mask_kernel<<<dim3(CPROC / 256, 8, BATCH), 256, 0, stream>>>(sbox, sarea, selcnt, mask);
    sweep_kernel<<<BATCH, 64, 0, stream>>>(sbox, sscore, sarea, selcnt, totval, mask,
                                           selkey, desc, boxes, score, out);
}

// Round 2
// 957.319 us; speedup vs baseline: 1.2926x; 1.2926x over previous
//
#include <hip/hip_runtime.h>
#include <stdint.h>

typedef unsigned long long u64;
typedef unsigned int u32;

#define BATCH 4
#define NANCH 230400          // 160*160*9
#define NBIN  8192            // 13-bit prefix histogram of descending key
#define KTARGET 4608          // top-K selection target (examined ~1100; 4x margin)
#define SELCAP 16384          // selection buffer cap per image
#define CPROC 4096            // candidates covered by pairwise bitmask (64 u64 words/row)
#define MAXD 1000
#define IMGW 1280.0f
#define IMGH 1280.0f

// ---- workspace layout (bytes). Total ~31.2 MB ----
#define HIST_OFF   0
#define SELCNT_OFF (BATCH*NBIN*4)                     // 131072
#define BSTAR_OFF  (SELCNT_OFF + BATCH*4)
#define TOTVAL_OFF (BSTAR_OFF + BATCH*4)
#define CTRL_BYTES (TOTVAL_OFF + BATCH*4)             // zeroed each launch
#define SCORE_OFF  131328                             // f32 [BATCH*NANCH]
#define DESC_OFF   (SCORE_OFF + BATCH*NANCH*4)        // u32 [BATCH*NANCH]
#define BOX_OFF    (DESC_OFF + BATCH*NANCH*4)         // float4 [BATCH*NANCH]
#define SELKEY_OFF (BOX_OFF + (size_t)BATCH*NANCH*16) // u64 [BATCH*SELCAP]
#define SBOX_OFF   (SELKEY_OFF + (size_t)BATCH*SELCAP*8)
#define SSCORE_OFF (SBOX_OFF + (size_t)BATCH*SELCAP*16)
#define SAREA_OFF  (SSCORE_OFF + (size_t)BATCH*SELCAP*4)
#define MASK_OFF   (SAREA_OFF + (size_t)BATCH*SELCAP*4)  // u64 [BATCH*CPROC*64]

// Decode: sigmoid score, box decode+clip, validity, sortable key, histogram.
// All rounding-sensitive ops via __f*_rn to match numpy f32 op-by-op (no contraction).
__global__ void decode_kernel(const float* __restrict__ obj,
                              const float4* __restrict__ deltas,
                              const float4* __restrict__ anchors,
                              float* __restrict__ score, u32* __restrict__ desc,
                              float4* __restrict__ boxes, u32* __restrict__ hist) {
    __shared__ u32 lh[NBIN];
    for (int i = threadIdx.x; i < NBIN; i += blockDim.x) lh[i] = 0;
    __syncthreads();
    int gid = blockIdx.x * blockDim.x + threadIdx.x;
    // N per image = 230400 = 900 blocks of 256 exactly -> no block spans 2 images
    if (gid < BATCH * NANCH) {
        float4 a = anchors[gid];
        float4 d = deltas[gid];
        float o = obj[gid];
        float w = __fsub_rn(a.z, a.x), h = __fsub_rn(a.w, a.y);
        float cx = __fadd_rn(a.x, __fmul_rn(0.5f, w));
        float cy = __fadd_rn(a.y, __fmul_rn(0.5f, h));
        float px = __fadd_rn(__fmul_rn(d.x, w), cx);
        float py = __fadd_rn(__fmul_rn(d.y, h), cy);
        float pw = __fmul_rn(expf(fminf(d.z, 4.0f)), w);
        float ph = __fmul_rn(expf(fminf(d.w, 4.0f)), h);
        float x1 = __fsub_rn(px, __fmul_rn(0.5f, pw));
        float y1 = __fsub_rn(py, __fmul_rn(0.5f, ph));
        float x2 = __fadd_rn(px, __fmul_rn(0.5f, pw));
        float y2 = __fadd_rn(py, __fmul_rn(0.5f, ph));
        x1 = fminf(fmaxf(x1, 0.0f), IMGW); x2 = fminf(fmaxf(x2, 0.0f), IMGW);
        y1 = fminf(fmaxf(y1, 0.0f), IMGH); y2 = fminf(fmaxf(y2, 0.0f), IMGH);
        bool valid = (__fsub_rn(x2, x1) >= 1.0f) && (__fsub_rn(y2, y1) >= 1.0f);
        float s = __fdiv_rn(1.0f, __fadd_rn(1.0f, expf(-o)));  // matches np sigmoid branch
        boxes[gid] = make_float4(x1, y1, x2, y2);
        score[gid] = s;
        // descending sortable key: score>0 so bits<0x80000000; smaller key = larger score
        u32 dsc = valid ? (0x7FFFFFFFu - __float_as_uint(s)) : 0xFFFFFFFFu;
        desc[gid] = dsc;
        if (valid) atomicAdd(&lh[dsc >> 19], 1u);
    }
    __syncthreads();
    int img = (blockIdx.x * blockDim.x) / NANCH;
    for (int i = threadIdx.x; i < NBIN; i += blockDim.x) {
        u32 v = lh[i];
        if (v) atomicAdd(&hist[img * NBIN + i], v);
    }
}

// Find per-image prefix bin b* : first bin with cumulative count >= KTARGET (prefix-closed top-K).
__global__ void select_kernel(const u32* __restrict__ hist, u32* __restrict__ bstar,
                              u32* __restrict__ totval) {
    int img = blockIdx.x, t = threadIdx.x;   // 256 threads
    const u32* H = hist + img * NBIN;
    __shared__ u32 part[256], excl[256], tot;
    u32 s = 0;
    for (int b = t * 32; b < t * 32 + 32; b++) s += H[b];
    part[t] = s;
    __syncthreads();
    if (t == 0) {
        u32 run = 0;
        for (int k = 0; k < 256; k++) { excl[k] = run; run += part[k]; }
        tot = run;
        totval[img] = run;
    }
    __syncthreads();
    u32 e = excl[t];
    if (e < KTARGET && e + part[t] >= KTARGET) {
        u32 cum = e;
        for (int b = t * 32; b < t * 32 + 32; b++) {
            cum += H[b];
            if (cum >= KTARGET) { bstar[img] = (u32)b; break; }
        }
    }
    if (t == 0 && tot < KTARGET) bstar[img] = 8190u;  // take all valid (invalid are bin 8191)
}

__global__ void compact_kernel(const u32* __restrict__ desc, const u32* __restrict__ bstar,
                               u32* __restrict__ selcnt, u64* __restrict__ selkey) {
    int gid = blockIdx.x * blockDim.x + threadIdx.x;
    if (gid >= BATCH * NANCH) return;
    int img = gid / NANCH;
    u32 d = desc[gid];
    if (d == 0xFFFFFFFFu) return;
    if ((d >> 19) <= bstar[img]) {
        u32 pos = atomicAdd(&selcnt[img], 1u);
        if (pos < SELCAP)
            selkey[(size_t)img * SELCAP + pos] = ((u64)d << 32) | (u32)(gid - img * NANCH);
    }
}

// Enumeration (rank-count) sort of selected items. Keys are unique ((key<<32)|idx),
// so rank is a perfect permutation. Scatter gathers box/score/area into sorted arrays.
__global__ void ranksort_kernel(const u64* __restrict__ selkey, const u32* __restrict__ selcnt,
                                const float4* __restrict__ boxes, const float* __restrict__ score,
                                float4* __restrict__ sbox, float* __restrict__ sscore,
                                float* __restrict__ sarea) {
    int img = blockIdx.y;
    int C = min((int)selcnt[img], SELCAP);
    if ((int)(blockIdx.x * 256) >= C) return;
    int i = blockIdx.x * 256 + threadIdx.x;
    const u64* K = selkey + (size_t)img * SELCAP;
    __shared__ u64 tile[1024];
    bool act = i < C;
    u64 my = act ? K[i] : ~0ull;
    u32 rank = 0;
    for (int t0 = 0; t0 < C; t0 += 1024) {
        int cnt = min(1024, C - t0);
        __syncthreads();
        for (int j = threadIdx.x; j < cnt; j += 256) tile[j] = K[t0 + j];
        __syncthreads();
        for (int j = 0; j < cnt; j++) rank += (tile[j] < my) ? 1u : 0u;
    }
    if (act) {
        int ai = (int)(my & 0xFFFFFFFFu);
        int g = img * NANCH + ai;
        float4 bx = boxes[g];
        size_t o = (size_t)img * SELCAP + rank;
        sbox[o] = bx;
        sscore[o] = score[g];
        sarea[o] = __fmul_rn(fmaxf(__fsub_rn(bx.z, bx.x), 0.0f),
                             fmaxf(__fsub_rn(bx.w, bx.y), 0.0f));
    }
}

// Pairwise IOU>0.5 bitmask over the first min(C,CPROC) sorted candidates.
// Row i, word w: bits for columns j in [w*64, w*64+64). Formula replicates reference f32 ops.
__global__ void mask_kernel(const float4* __restrict__ sbox, const float* __restrict__ sarea,
                            const u32* __restrict__ selcnt, u64* __restrict__ mask) {
    int img = blockIdx.z;
    int C = min((int)selcnt[img], SELCAP);
    int Ce = min(C, CPROC);
    if ((int)(blockIdx.x * 256) >= Ce) return;
    int jtmax = (Ce + 63) >> 6;
    int jt0 = blockIdx.y * 8, jt1 = min(jt0 + 8, jtmax);
    if (jt0 >= jtmax) return;
    int i = blockIdx.x * 256 + threadIdx.x;
    const float4* SB = sbox + (size_t)img * SELCAP;
    const float* SA = sarea + (size_t)img * SELCAP;
    __shared__ float jx1[64], jy1[64], jx2[64], jy2[64], jar[64];
    bool act = i < Ce;
    float4 bi = make_float4(0, 0, 0, 0);
    float ai_ = 0.0f;
    if (act) { bi = SB[i]; ai_ = SA[i]; }
    u64* Mrow = mask + ((size_t)img * CPROC + (size_t)i) * 64;
    for (int jt = jt0; jt < jt1; jt++) {
        int jbase = jt << 6;
        int jcnt = min(64, Ce - jbase);
        __syncthreads();
        if (threadIdx.x < 64) {
            int l = threadIdx.x;
            if (l < jcnt) {
                float4 b = SB[jbase + l];
                jx1[l] = b.x; jy1[l] = b.y; jx2[l] = b.z; jy2[l] = b.w;
                jar[l] = SA[jbase + l];
            } else {
                jx1[l] = 0; jy1[l] = 0; jx2[l] = 0; jy2[l] = 0; jar[l] = 0;
            }
        }
        __syncthreads();
        if (act) {
            u64 bits = 0;
            for (int jl = 0; jl < jcnt; jl++) {
                float ix1 = fmaxf(bi.x, jx1[jl]);
                float iy1 = fmaxf(bi.y, jy1[jl]);
                float ix2 = fminf(bi.z, jx2[jl]);
                float iy2 = fminf(bi.w, jy2[jl]);
                float inter = __fmul_rn(fmaxf(__fsub_rn(ix2, ix1), 0.0f),
                                        fmaxf(__fsub_rn(iy2, iy1), 0.0f));
                float den = __fadd_rn(__fsub_rn(__fadd_rn(ai_, jar[jl]), inter), 1e-9f);
                if (__fdiv_rn(inter, den) > 0.5f) bits |= (1ull << jl);
            }
            Mrow[jt] = bits;
        }
    }
}

__device__ __forceinline__ bool supp_by_acc(float4 bx, float ar, int acc, int lane,
                                            const float* ax1, const float* ay1,
                                            const float* ax2, const float* ay2,
                                            const float* aar) {
    bool hit = false;
    for (int k = lane; k < acc; k += 64) {
        float ix1 = fmaxf(bx.x, ax1[k]);
        float iy1 = fmaxf(bx.y, ay1[k]);
        float ix2 = fminf(bx.z, ax2[k]);
        float iy2 = fminf(bx.w, ay2[k]);
        float inter = __fmul_rn(fmaxf(__fsub_rn(ix2, ix1), 0.0f),
                                fmaxf(__fsub_rn(iy2, iy1), 0.0f));
        float den = __fadd_rn(__fsub_rn(__fadd_rn(aar[k], ar), inter), 1e-9f);
        if (__fdiv_rn(inter, den) > 0.5f) { hit = true; break; }
    }
    return __ballot(hit) != 0ull;
}

// One wave per image. Suppressed bitset for CPROC candidates: lane l holds word l.
// Per 64-block: serial bit-resolve in-register (the irreducible NMS chain), then
// BATCHED suppression-row ORs (4-way unrolled, loads pipelined) and LANE-PARALLEL
// output writes (lane j handles the j-th accepted bit).  [R1: was fully serial,
// ~1200 cy/accepted -> 519 us; this removes the per-accepted vmcnt(0) stalls.]
__global__ void sweep_kernel(const float4* __restrict__ sbox, const float* __restrict__ sscore,
                             const float* __restrict__ sarea, const u32* __restrict__ selcnt,
                             const u32* __restrict__ totval, const u64* __restrict__ mask,
                             const u64* __restrict__ selkey, const u32* __restrict__ descarr,
                             const float4* __restrict__ boxes, const float* __restrict__ scorearr,
                             float* __restrict__ out) {
    int img = blockIdx.x, lane = threadIdx.x;  // 64 threads
    int C = min((int)selcnt[img], SELCAP);
    int Ce = min(C, CPROC);
    const float4* SB = sbox + (size_t)img * SELCAP;
    const float* SS = sscore + (size_t)img * SELCAP;
    const float* SA = sarea + (size_t)img * SELCAP;
    const u64* M = mask + (size_t)img * CPROC * 64;
    __shared__ float ax1[MAXD], ay1[MAXD], ax2[MAXD], ay2[MAXD], aar[MAXD];
    float* ob = out + (size_t)img * MAXD * 4;
    float* os = out + (size_t)BATCH * MAXD * 4 + (size_t)img * MAXD;
    float* ov = out + (size_t)BATCH * MAXD * 5 + (size_t)img * MAXD;
    u64 sup = 0;
    int acc = 0;
    int nblk = (Ce + 63) >> 6;
    for (int ib = 0; ib < nblk && acc < MAXD; ib++) {
        int base = ib << 6;
        int bcount = min(64, Ce - base);
        u64 tile = 0;
        if (lane < bcount) tile = M[(size_t)(base + lane) * 64 + ib];
        u64 cur = __shfl(sup, ib), newm = 0;
        int na = 0;
        for (int b = 0; b < bcount; b++) {           // uniform across lanes
            if (acc + na >= MAXD) break;
            if (!((cur >> b) & 1ull)) {
                newm |= (1ull << b);
                na++;
                cur |= __shfl(tile, b);              // row (base+b)'s intra-block bits
            }
        }
        // batched suppression-row OR: 4 independent loads in flight per trip
        u64 mm = newm, orv = 0;
        while (mm) {
            int b0 = __builtin_ctzll(mm); mm &= mm - 1;
            u64 v0 = M[(size_t)(base + b0) * 64 + lane], v1 = 0, v2 = 0, v3 = 0;
            if (mm) { int b1 = __builtin_ctzll(mm); mm &= mm - 1;
                      v1 = M[(size_t)(base + b1) * 64 + lane]; }
            if (mm) { int b2 = __builtin_ctzll(mm); mm &= mm - 1;
                      v2 = M[(size_t)(base + b2) * 64 + lane]; }
            if (mm) { int b3 = __builtin_ctzll(mm); mm &= mm - 1;
                      v3 = M[(size_t)(base + b3) * 64 + lane]; }
            orv |= (v0 | v1) | (v2 | v3);
        }
        sup |= orv;
        // lane-parallel outputs: lane j takes the j-th set bit of newm
        if (lane < na) {
            u64 sel = newm;
            for (int k = 0; k < lane; k++) sel &= sel - 1;
            int i = base + __builtin_ctzll(sel);
            int o = acc + lane;
            float4 bx = SB[i];
            ((float4*)ob)[o] = bx;
            os[o] = SS[i]; ov[o] = 1.0f;
            ax1[o] = bx.x; ay1[o] = bx.y; ax2[o] = bx.z; ay2[o] = bx.w;
            aar[o] = SA[i];
        }
        acc += na;
        __syncthreads();   // order cross-lane LDS accept-array writes (1 wave: cheap)
    }
    __syncthreads();
    // Continuation A (exact, rarely taken): selected candidates beyond the mask window.
    for (int i = Ce; i < C && acc < MAXD; i++) {
        float4 bx = SB[i];
        float ar = SA[i];
        if (!supp_by_acc(bx, ar, acc, lane, ax1, ay1, ax2, ay2, aar)) {
            if (lane == 0) {
                ob[acc * 4 + 0] = bx.x; ob[acc * 4 + 1] = bx.y;
                ob[acc * 4 + 2] = bx.z; ob[acc * 4 + 3] = bx.w;
                os[acc] = SS[i]; ov[acc] = 1.0f;
                ax1[acc] = bx.x; ay1[acc] = bx.y; ax2[acc] = bx.z; ay2[acc] = bx.w;
                aar[acc] = SA[i];
            }
            __syncthreads();
            acc++;
        }
    }
    // Continuation B (exact deep fallback, ~never taken): valid candidates beyond selection.
    u32 tv = totval[img];
    if (acc < MAXD && (u32)C < tv && (u32)C == selcnt[img]) {
        u64 lk = 0;
        for (int j = lane; j < C; j += 64) lk = max(lk, selkey[(size_t)img * SELCAP + j]);
        for (int off = 32; off; off >>= 1) {
            u64 o = __shfl_down(lk, off);
            lk = max(lk, o);
        }
        lk = __shfl(lk, 0);
        while (acc < MAXD) {
            u64 best = ~0ull;
            for (int j = lane; j < NANCH; j += 64) {
                u32 d = descarr[(size_t)img * NANCH + j];
                if (d != 0xFFFFFFFFu) {
                    u64 k = ((u64)d << 32) | (u32)j;
                    if (k > lk && k < best) best = k;
                }
            }
            for (int off = 32; off; off >>= 1) {
                u64 o = __shfl_down(best, off);
                best = min(best, o);
            }
            best = __shfl(best, 0);
            if (best == ~0ull) break;
            lk = best;
            int ai = (int)(best & 0xFFFFFFFFu);
            int g = img * NANCH + ai;
            float4 bx = boxes[g];
            float ar = __fmul_rn(fmaxf(__fsub_rn(bx.z, bx.x), 0.0f),
                                 fmaxf(__fsub_rn(bx.w, bx.y), 0.0f));
            if (!supp_by_acc(bx, ar, acc, lane, ax1, ay1, ax2, ay2, aar)) {
                if (lane == 0) {
                    ob[acc * 4 + 0] = bx.x; ob[acc * 4 + 1] = bx.y;
                    ob[acc * 4 + 2] = bx.z; ob[acc * 4 + 3] = bx.w;
                    os[acc] = scorearr[g]; ov[acc] = 1.0f;
                    ax1[acc] = bx.x; ay1[acc] = bx.y; ax2[acc] = bx.z; ay2[acc] = bx.w;
                    aar[acc] = ar;
                }
                __syncthreads();
                acc++;
            }
        }
    }
}

extern "C" void kernel_launch(void* const* d_in, const int* in_sizes, int n_in,
                              void* d_out, int out_size, void* d_ws, size_t ws_size,
                              hipStream_t stream) {
    const float* obj = (const float*)d_in[0];
    const float4* deltas = (const float4*)d_in[1];
    const float4* anchors = (const float4*)d_in[2];
    char* ws = (char*)d_ws;
    u32* hist = (u32*)(ws + HIST_OFF);
    u32* selcnt = (u32*)(ws + SELCNT_OFF);
    u32* bstar = (u32*)(ws + BSTAR_OFF);
    u32* totval = (u32*)(ws + TOTVAL_OFF);
    float* score = (float*)(ws + SCORE_OFF);
    u32* desc = (u32*)(ws + DESC_OFF);
    float4* boxes = (float4*)(ws + BOX_OFF);
    u64* selkey = (u64*)(ws + SELKEY_OFF);
    float4* sbox = (float4*)(ws + SBOX_OFF);
    float* sscore = (float*)(ws + SSCORE_OFF);
    float* sarea = (float*)(ws + SAREA_OFF);
    u64* mask = (u64*)(ws + MASK_OFF);
    float* out = (float*)d_out;

    hipMemsetAsync(ws + HIST_OFF, 0, CTRL_BYTES, stream);                  // hist + counters
    hipMemsetAsync(d_out, 0, (size_t)out_size * sizeof(float), stream);    // zero-padded outputs

    decode_kernel<<<3600, 256, 0, stream>>>(obj, deltas, anchors, score, desc, boxes, hist);
    select_kernel<<<BATCH, 256, 0, stream>>>(hist, bstar, totval);
    compact_kernel<<<3600, 256, 0, stream>>>(desc, bstar, selcnt, selkey);
    ranksort_kernel<<<dim3(SELCAP / 256, BATCH), 256, 0, stream>>>(selkey, selcnt, boxes, score,
                                                                   sbox, sscore, sarea);
    mask_kernel<<<dim3(CPROC / 256, 8, BATCH), 256, 0, stream>>>(sbox, sarea, selcnt, mask);
    sweep_kernel<<<BATCH, 64, 0, stream>>>(sbox, sscore, sarea, selcnt, totval, mask,
                                           selkey, desc, boxes, score, out);
}

// Round 3
// 486.722 us; speedup vs baseline: 2.5424x; 1.9669x over previous
//
#include <hip/hip_runtime.h>
#include <stdint.h>

typedef unsigned long long u64;
typedef unsigned int u32;

#define BATCH 4
#define NANCH 230400          // 160*160*9
#define NBLK  900             // blocks of 256 per image (exact)
#define SELCAP 16384          // selection buffer cap per image
#define CPROC 4096            // candidates covered by pairwise bitmask (64 u64 words/row)
#define MAXD 1000
#define IMGW 1280.0f
#define IMGH 1280.0f

// Fixed selection threshold: score >= 0.880797 (= sigmoid(2.0), float bits 0x3F617BE1).
// desc key = 0x7FFFFFFF - float_bits(score), so pass <=> desc <= DSC_TH.
// Expected passers/image = 230400 * P(N(0,1)>2) = 5242 +- 72; NMS examines ~1150.
// Prefix-closed in key space; exact Continuations A/B in sweep cover any shortfall.
#define DSC_TH 0x409E841Eu

// ---- workspace layout (bytes). Total ~31.2 MB ----
#define BLKCNT_OFF 0                                   // u32 [BATCH*NBLK]
#define BLKVAL_OFF (BLKCNT_OFF + BATCH*NBLK*4)
#define BLKOFF_OFF (BLKVAL_OFF + BATCH*NBLK*4)
#define SELCNT_OFF (BLKOFF_OFF + BATCH*NBLK*4)         // u32 [BATCH]
#define TOTVAL_OFF (SELCNT_OFF + BATCH*4)
#define SCORE_OFF  65536                               // f32 [BATCH*NANCH]
#define DESC_OFF   (SCORE_OFF + BATCH*NANCH*4)         // u32 [BATCH*NANCH]
#define BOX_OFF    (DESC_OFF + BATCH*NANCH*4)          // float4 [BATCH*NANCH]
#define SELKEY_OFF (BOX_OFF + (size_t)BATCH*NANCH*16)  // u64 [BATCH*SELCAP]
#define SBOX_OFF   (SELKEY_OFF + (size_t)BATCH*SELCAP*8)
#define SSCORE_OFF (SBOX_OFF + (size_t)BATCH*SELCAP*16)
#define SAREA_OFF  (SSCORE_OFF + (size_t)BATCH*SELCAP*4)
#define MASK_OFF   (SAREA_OFF + (size_t)BATCH*SELCAP*4)   // u64 [BATCH*CPROC*64]

// Decode: sigmoid score, box decode+clip, validity, sortable key, per-block
// pass/valid counts via ballot (NO atomics, no LDS histogram — R2: the hist
// flush + compact atomicAdd were ~900 us of contended same-line atomics).
// All rounding-sensitive ops via __f*_rn to match numpy f32 op-by-op.
__global__ void decode_kernel(const float* __restrict__ obj,
                              const float4* __restrict__ deltas,
                              const float4* __restrict__ anchors,
                              float* __restrict__ score, u32* __restrict__ desc,
                              float4* __restrict__ boxes,
                              u32* __restrict__ blockcnt, u32* __restrict__ blockval) {
    int gid = blockIdx.x * blockDim.x + threadIdx.x;   // grid exact: 3600*256
    float4 a = anchors[gid];
    float4 d = deltas[gid];
    float o = obj[gid];
    float w = __fsub_rn(a.z, a.x), h = __fsub_rn(a.w, a.y);
    float cx = __fadd_rn(a.x, __fmul_rn(0.5f, w));
    float cy = __fadd_rn(a.y, __fmul_rn(0.5f, h));
    float px = __fadd_rn(__fmul_rn(d.x, w), cx);
    float py = __fadd_rn(__fmul_rn(d.y, h), cy);
    float pw = __fmul_rn(expf(fminf(d.z, 4.0f)), w);
    float ph = __fmul_rn(expf(fminf(d.w, 4.0f)), h);
    float x1 = __fsub_rn(px, __fmul_rn(0.5f, pw));
    float y1 = __fsub_rn(py, __fmul_rn(0.5f, ph));
    float x2 = __fadd_rn(px, __fmul_rn(0.5f, pw));
    float y2 = __fadd_rn(py, __fmul_rn(0.5f, ph));
    x1 = fminf(fmaxf(x1, 0.0f), IMGW); x2 = fminf(fmaxf(x2, 0.0f), IMGW);
    y1 = fminf(fmaxf(y1, 0.0f), IMGH); y2 = fminf(fmaxf(y2, 0.0f), IMGH);
    bool valid = (__fsub_rn(x2, x1) >= 1.0f) && (__fsub_rn(y2, y1) >= 1.0f);
    float s = __fdiv_rn(1.0f, __fadd_rn(1.0f, expf(-o)));  // matches np sigmoid branch
    boxes[gid] = make_float4(x1, y1, x2, y2);
    score[gid] = s;
    u32 dsc = valid ? (0x7FFFFFFFu - __float_as_uint(s)) : 0xFFFFFFFFu;
    desc[gid] = dsc;
    bool pass = dsc <= DSC_TH;
    u64 bp = __ballot(pass);
    u64 bv = __ballot(valid);
    __shared__ u32 wcnt[4], wval[4];
    int wid = threadIdx.x >> 6;
    if ((threadIdx.x & 63) == 0) { wcnt[wid] = (u32)__popcll(bp); wval[wid] = (u32)__popcll(bv); }
    __syncthreads();
    if (threadIdx.x == 0) {
        blockcnt[blockIdx.x] = wcnt[0] + wcnt[1] + wcnt[2] + wcnt[3];
        blockval[blockIdx.x] = wval[0] + wval[1] + wval[2] + wval[3];
    }
}

// Per-image exclusive prefix over the 900 block counts (one block per image).
__global__ void scan_kernel(const u32* __restrict__ blockcnt, const u32* __restrict__ blockval,
                            u32* __restrict__ blockoff, u32* __restrict__ selcnt,
                            u32* __restrict__ totval) {
    int img = blockIdx.x, t = threadIdx.x;   // 256 threads
    const u32* BC = blockcnt + img * NBLK;
    u32* BO = blockoff + img * NBLK;
    __shared__ u32 part[256], excl[256], tot;
    int i0 = t * 4;                           // 4*256 = 1024 >= 900
    u32 c[4], s = 0;
    for (int k = 0; k < 4; k++) { int i = i0 + k; c[k] = (i < NBLK) ? BC[i] : 0u; s += c[k]; }
    part[t] = s;
    __syncthreads();
    if (t == 0) {
        u32 run = 0;
        for (int k = 0; k < 256; k++) { excl[k] = run; run += part[k]; }
        tot = run;
    }
    __syncthreads();
    u32 run = excl[t];
    for (int k = 0; k < 4; k++) { int i = i0 + k; if (i < NBLK) BO[i] = run; run += c[k]; }
    if (t == 0) selcnt[img] = tot;
    __syncthreads();
    u32 v = 0;
    for (int k = 0; k < 4; k++) { int i = i0 + k; if (i < NBLK) v += blockval[img * NBLK + i]; }
    part[t] = v;
    __syncthreads();
    if (t == 0) {
        u32 r = 0;
        for (int k = 0; k < 256; k++) r += part[k];
        totval[img] = r;
    }
}

// Deterministic scatter: position = block offset + intra-block ballot prefix. No atomics.
__global__ void scatter_kernel(const u32* __restrict__ desc, const u32* __restrict__ blockoff,
                               u64* __restrict__ selkey) {
    int blk = blockIdx.x, tid = threadIdx.x;
    int gid = blk * 256 + tid;
    int img = blk / NBLK;
    u32 d = desc[gid];
    bool pass = d <= DSC_TH;
    u64 bal = __ballot(pass);
    int lane = tid & 63, wid = tid >> 6;
    __shared__ u32 woff[4];
    if (lane == 0) woff[wid] = (u32)__popcll(bal);
    __syncthreads();
    u32 wbase = 0;
    for (int w = 0; w < wid; w++) wbase += woff[w];
    if (pass) {
        u32 pos = blockoff[blk] + wbase + (u32)__popcll(bal & ((1ull << lane) - 1ull));
        if (pos < SELCAP)
            selkey[(size_t)img * SELCAP + pos] = ((u64)d << 32) | (u32)(gid - img * NANCH);
    }
}

// Enumeration (rank-count) sort of selected items. Keys are unique ((key<<32)|idx),
// so rank is a perfect permutation. Scatter gathers box/score/area into sorted arrays.
__global__ void ranksort_kernel(const u64* __restrict__ selkey, const u32* __restrict__ selcnt,
                                const float4* __restrict__ boxes, const float* __restrict__ score,
                                float4* __restrict__ sbox, float* __restrict__ sscore,
                                float* __restrict__ sarea) {
    int img = blockIdx.y;
    int C = min((int)selcnt[img], SELCAP);
    if ((int)(blockIdx.x * 256) >= C) return;
    int i = blockIdx.x * 256 + threadIdx.x;
    const u64* K = selkey + (size_t)img * SELCAP;
    __shared__ u64 tile[1024];
    bool act = i < C;
    u64 my = act ? K[i] : ~0ull;
    u32 rank = 0;
    for (int t0 = 0; t0 < C; t0 += 1024) {
        int cnt = min(1024, C - t0);
        __syncthreads();
        for (int j = threadIdx.x; j < cnt; j += 256) tile[j] = K[t0 + j];
        __syncthreads();
        for (int j = 0; j < cnt; j++) rank += (tile[j] < my) ? 1u : 0u;
    }
    if (act) {
        int ai = (int)(my & 0xFFFFFFFFu);
        int g = img * NANCH + ai;
        float4 bx = boxes[g];
        size_t o = (size_t)img * SELCAP + rank;
        sbox[o] = bx;
        sscore[o] = score[g];
        sarea[o] = __fmul_rn(fmaxf(__fsub_rn(bx.z, bx.x), 0.0f),
                             fmaxf(__fsub_rn(bx.w, bx.y), 0.0f));
    }
}

// Pairwise IOU>0.5 bitmask over the first min(C,CPROC) sorted candidates.
// Row i, word w: bits for columns j in [w*64, w*64+64). Formula replicates reference f32 ops.
__global__ void mask_kernel(const float4* __restrict__ sbox, const float* __restrict__ sarea,
                            const u32* __restrict__ selcnt, u64* __restrict__ mask) {
    int img = blockIdx.z;
    int C = min((int)selcnt[img], SELCAP);
    int Ce = min(C, CPROC);
    if ((int)(blockIdx.x * 256) >= Ce) return;
    int jtmax = (Ce + 63) >> 6;
    int jt0 = blockIdx.y * 8, jt1 = min(jt0 + 8, jtmax);
    if (jt0 >= jtmax) return;
    int i = blockIdx.x * 256 + threadIdx.x;
    const float4* SB = sbox + (size_t)img * SELCAP;
    const float* SA = sarea + (size_t)img * SELCAP;
    __shared__ float jx1[64], jy1[64], jx2[64], jy2[64], jar[64];
    bool act = i < Ce;
    float4 bi = make_float4(0, 0, 0, 0);
    float ai_ = 0.0f;
    if (act) { bi = SB[i]; ai_ = SA[i]; }
    u64* Mrow = mask + ((size_t)img * CPROC + (size_t)i) * 64;
    for (int jt = jt0; jt < jt1; jt++) {
        int jbase = jt << 6;
        int jcnt = min(64, Ce - jbase);
        __syncthreads();
        if (threadIdx.x < 64) {
            int l = threadIdx.x;
            if (l < jcnt) {
                float4 b = SB[jbase + l];
                jx1[l] = b.x; jy1[l] = b.y; jx2[l] = b.z; jy2[l] = b.w;
                jar[l] = SA[jbase + l];
            } else {
                jx1[l] = 0; jy1[l] = 0; jx2[l] = 0; jy2[l] = 0; jar[l] = 0;
            }
        }
        __syncthreads();
        if (act) {
            u64 bits = 0;
            for (int jl = 0; jl < jcnt; jl++) {
                float ix1 = fmaxf(bi.x, jx1[jl]);
                float iy1 = fmaxf(bi.y, jy1[jl]);
                float ix2 = fminf(bi.z, jx2[jl]);
                float iy2 = fminf(bi.w, jy2[jl]);
                float inter = __fmul_rn(fmaxf(__fsub_rn(ix2, ix1), 0.0f),
                                        fmaxf(__fsub_rn(iy2, iy1), 0.0f));
                float den = __fadd_rn(__fsub_rn(__fadd_rn(ai_, jar[jl]), inter), 1e-9f);
                if (__fdiv_rn(inter, den) > 0.5f) bits |= (1ull << jl);
            }
            Mrow[jt] = bits;
        }
    }
}

__device__ __forceinline__ bool supp_by_acc(float4 bx, float ar, int acc, int lane,
                                            const float* ax1, const float* ay1,
                                            const float* ax2, const float* ay2,
                                            const float* aar) {
    bool hit = false;
    for (int k = lane; k < acc; k += 64) {
        float ix1 = fmaxf(bx.x, ax1[k]);
        float iy1 = fmaxf(bx.y, ay1[k]);
        float ix2 = fminf(bx.z, ax2[k]);
        float iy2 = fminf(bx.w, ay2[k]);
        float inter = __fmul_rn(fmaxf(__fsub_rn(ix2, ix1), 0.0f),
                                fmaxf(__fsub_rn(iy2, iy1), 0.0f));
        float den = __fadd_rn(__fsub_rn(__fadd_rn(aar[k], ar), inter), 1e-9f);
        if (__fdiv_rn(inter, den) > 0.5f) { hit = true; break; }
    }
    return __ballot(hit) != 0ull;
}

// One wave per image. Suppressed bitset for CPROC candidates: lane l holds word l.
// Per 64-block: serial bit-resolve in-register (the irreducible NMS chain), then
// batched suppression-row ORs (4-way unrolled) and lane-parallel output writes.
__global__ void sweep_kernel(const float4* __restrict__ sbox, const float* __restrict__ sscore,
                             const float* __restrict__ sarea, const u32* __restrict__ selcnt,
                             const u32* __restrict__ totval, const u64* __restrict__ mask,
                             const u64* __restrict__ selkey, const u32* __restrict__ descarr,
                             const float4* __restrict__ boxes, const float* __restrict__ scorearr,
                             float* __restrict__ out) {
    int img = blockIdx.x, lane = threadIdx.x;  // 64 threads
    int C = min((int)selcnt[img], SELCAP);
    int Ce = min(C, CPROC);
    const float4* SB = sbox + (size_t)img * SELCAP;
    const float* SS = sscore + (size_t)img * SELCAP;
    const float* SA = sarea + (size_t)img * SELCAP;
    const u64* M = mask + (size_t)img * CPROC * 64;
    __shared__ float ax1[MAXD], ay1[MAXD], ax2[MAXD], ay2[MAXD], aar[MAXD];
    float* ob = out + (size_t)img * MAXD * 4;
    float* os = out + (size_t)BATCH * MAXD * 4 + (size_t)img * MAXD;
    float* ov = out + (size_t)BATCH * MAXD * 5 + (size_t)img * MAXD;
    u64 sup = 0;
    int acc = 0;
    int nblk = (Ce + 63) >> 6;
    for (int ib = 0; ib < nblk && acc < MAXD; ib++) {
        int base = ib << 6;
        int bcount = min(64, Ce - base);
        u64 tile = 0;
        if (lane < bcount) tile = M[(size_t)(base + lane) * 64 + ib];
        u64 cur = __shfl(sup, ib), newm = 0;
        int na = 0;
        for (int b = 0; b < bcount; b++) {           // uniform across lanes
            if (acc + na >= MAXD) break;
            if (!((cur >> b) & 1ull)) {
                newm |= (1ull << b);
                na++;
                cur |= __shfl(tile, b);              // row (base+b)'s intra-block bits
            }
        }
        // batched suppression-row OR: 4 independent loads in flight per trip
        u64 mm = newm, orv = 0;
        while (mm) {
            int b0 = __builtin_ctzll(mm); mm &= mm - 1;
            u64 v0 = M[(size_t)(base + b0) * 64 + lane], v1 = 0, v2 = 0, v3 = 0;
            if (mm) { int b1 = __builtin_ctzll(mm); mm &= mm - 1;
                      v1 = M[(size_t)(base + b1) * 64 + lane]; }
            if (mm) { int b2 = __builtin_ctzll(mm); mm &= mm - 1;
                      v2 = M[(size_t)(base + b2) * 64 + lane]; }
            if (mm) { int b3 = __builtin_ctzll(mm); mm &= mm - 1;
                      v3 = M[(size_t)(base + b3) * 64 + lane]; }
            orv |= (v0 | v1) | (v2 | v3);
        }
        sup |= orv;
        // lane-parallel outputs: lane j takes the j-th set bit of newm
        if (lane < na) {
            u64 sel = newm;
            for (int k = 0; k < lane; k++) sel &= sel - 1;
            int i = base + __builtin_ctzll(sel);
            int o = acc + lane;
            float4 bx = SB[i];
            ((float4*)ob)[o] = bx;
            os[o] = SS[i]; ov[o] = 1.0f;
            ax1[o] = bx.x; ay1[o] = bx.y; ax2[o] = bx.z; ay2[o] = bx.w;
            aar[o] = SA[i];
        }
        acc += na;
        __syncthreads();   // order cross-lane LDS accept-array writes (1 wave: cheap)
    }
    __syncthreads();
    // Continuation A (exact, rarely taken): selected candidates beyond the mask window.
    for (int i = Ce; i < C && acc < MAXD; i++) {
        float4 bx = SB[i];
        float ar = SA[i];
        if (!supp_by_acc(bx, ar, acc, lane, ax1, ay1, ax2, ay2, aar)) {
            if (lane == 0) {
                ob[acc * 4 + 0] = bx.x; ob[acc * 4 + 1] = bx.y;
                ob[acc * 4 + 2] = bx.z; ob[acc * 4 + 3] = bx.w;
                os[acc] = SS[i]; ov[acc] = 1.0f;
                ax1[acc] = bx.x; ay1[acc] = bx.y; ax2[acc] = bx.z; ay2[acc] = bx.w;
                aar[acc] = SA[i];
            }
            __syncthreads();
            acc++;
        }
    }
    // Continuation B (exact deep fallback, ~never taken): valid candidates beyond selection.
    u32 tv = totval[img];
    if (acc < MAXD && (u32)C < tv && (u32)C == selcnt[img]) {
        u64 lk = 0;
        for (int j = lane; j < C; j += 64) lk = max(lk, selkey[(size_t)img * SELCAP + j]);
        for (int off = 32; off; off >>= 1) {
            u64 o = __shfl_down(lk, off);
            lk = max(lk, o);
        }
        lk = __shfl(lk, 0);
        while (acc < MAXD) {
            u64 best = ~0ull;
            for (int j = lane; j < NANCH; j += 64) {
                u32 d = descarr[(size_t)img * NANCH + j];
                if (d != 0xFFFFFFFFu) {
                    u64 k = ((u64)d << 32) | (u32)j;
                    if (k > lk && k < best) best = k;
                }
            }
            for (int off = 32; off; off >>= 1) {
                u64 o = __shfl_down(best, off);
                best = min(best, o);
            }
            best = __shfl(best, 0);
            if (best == ~0ull) break;
            lk = best;
            int ai = (int)(best & 0xFFFFFFFFu);
            int g = img * NANCH + ai;
            float4 bx = boxes[g];
            float ar = __fmul_rn(fmaxf(__fsub_rn(bx.z, bx.x), 0.0f),
                                 fmaxf(__fsub_rn(bx.w, bx.y), 0.0f));
            if (!supp_by_acc(bx, ar, acc, lane, ax1, ay1, ax2, ay2, aar)) {
                if (lane == 0) {
                    ob[acc * 4 + 0] = bx.x; ob[acc * 4 + 1] = bx.y;
                    ob[acc * 4 + 2] = bx.z; ob[acc * 4 + 3] = bx.w;
                    os[acc] = scorearr[g]; ov[acc] = 1.0f;
                    ax1[acc] = bx.x; ay1[acc] = bx.y; ax2[acc] = bx.z; ay2[acc] = bx.w;
                    aar[acc] = ar;
                }
                __syncthreads();
                acc++;
            }
        }
    }
}

extern "C" void kernel_launch(void* const* d_in, const int* in_sizes, int n_in,
                              void* d_out, int out_size, void* d_ws, size_t ws_size,
                              hipStream_t stream) {
    const float* obj = (const float*)d_in[0];
    const float4* deltas = (const float4*)d_in[1];
    const float4* anchors = (const float4*)d_in[2];
    char* ws = (char*)d_ws;
    u32* blockcnt = (u32*)(ws + BLKCNT_OFF);
    u32* blockval = (u32*)(ws + BLKVAL_OFF);
    u32* blockoff = (u32*)(ws + BLKOFF_OFF);
    u32* selcnt = (u32*)(ws + SELCNT_OFF);
    u32* totval = (u32*)(ws + TOTVAL_OFF);
    float* score = (float*)(ws + SCORE_OFF);
    u32* desc = (u32*)(ws + DESC_OFF);
    float4* boxes = (float4*)(ws + BOX_OFF);
    u64* selkey = (u64*)(ws + SELKEY_OFF);
    float4* sbox = (float4*)(ws + SBOX_OFF);
    float* sscore = (float*)(ws + SSCORE_OFF);
    float* sarea = (float*)(ws + SAREA_OFF);
    u64* mask = (u64*)(ws + MASK_OFF);
    float* out = (float*)d_out;

    hipMemsetAsync(d_out, 0, (size_t)out_size * sizeof(float), stream);    // zero-padded outputs

    decode_kernel<<<3600, 256, 0, stream>>>(obj, deltas, anchors, score, desc, boxes,
                                            blockcnt, blockval);
    scan_kernel<<<BATCH, 256, 0, stream>>>(blockcnt, blockval, blockoff, selcnt, totval);
    scatter_kernel<<<3600, 256, 0, stream>>>(desc, blockoff, selkey);
    ranksort_kernel<<<dim3(SELCAP / 256, BATCH), 256, 0, stream>>>(selkey, selcnt, boxes, score,
                                                                   sbox, sscore, sarea);
    mask_kernel<<<dim3(CPROC / 256, 8, BATCH), 256, 0, stream>>>(sbox, sarea, selcnt, mask);
    sweep_kernel<<<BATCH, 64, 0, stream>>>(sbox, sscore, sarea, selcnt, totval, mask,
                                           selkey, desc, boxes, score, out);
}

// Round 4
// 312.378 us; speedup vs baseline: 3.9613x; 1.5581x over previous
//
#include <hip/hip_runtime.h>
#include <stdint.h>

typedef unsigned long long u64;
typedef unsigned int u32;

#define BATCH 4
#define NANCH 230400          // 160*160*9
#define NBLK  900             // blocks of 256 per image (exact)
#define SELCAP 16384          // selection buffer cap per image
#define CPROC 4096            // candidates covered by pairwise bitmask (64 u64 words/row)
#define MAXD 1000
#define IMGW 1280.0f
#define IMGH 1280.0f

// Fixed selection threshold: score >= 0.880797 (= sigmoid(2.0), float bits 0x3F617BE1).
// desc key = 0x7FFFFFFF - float_bits(score), so pass <=> desc <= DSC_TH.
// Expected passers/image = 230400 * P(N(0,1)>2) = 5242 +- 72; NMS examines ~1150.
// Prefix-closed in key space; exact Continuations A/B in sweep cover any shortfall.
#define DSC_TH 0x409E841Eu

// ---- workspace layout (bytes). Total ~31.2 MB ----
#define BLKCNT_OFF 0                                   // u32 [BATCH*NBLK]
#define BLKVAL_OFF (BLKCNT_OFF + BATCH*NBLK*4)
#define BLKOFF_OFF (BLKVAL_OFF + BATCH*NBLK*4)
#define SELCNT_OFF (BLKOFF_OFF + BATCH*NBLK*4)         // u32 [BATCH]
#define TOTVAL_OFF (SELCNT_OFF + BATCH*4)
#define SCORE_OFF  65536                               // f32 [BATCH*NANCH]
#define DESC_OFF   (SCORE_OFF + BATCH*NANCH*4)         // u32 [BATCH*NANCH]
#define BOX_OFF    (DESC_OFF + BATCH*NANCH*4)          // float4 [BATCH*NANCH]
#define SELKEY_OFF (BOX_OFF + (size_t)BATCH*NANCH*16)  // u64 [BATCH*SELCAP]
#define SBOX_OFF   (SELKEY_OFF + (size_t)BATCH*SELCAP*8)
#define SSCORE_OFF (SBOX_OFF + (size_t)BATCH*SELCAP*16)
#define SAREA_OFF  (SSCORE_OFF + (size_t)BATCH*SELCAP*4)
#define MASK_OFF   (SAREA_OFF + (size_t)BATCH*SELCAP*4)   // u64 [BATCH*CPROC*64]

// Decode: sigmoid score, box decode+clip, validity, sortable key, per-block
// pass/valid counts via ballot (no atomics). All rounding-sensitive ops via
// __f*_rn to match numpy f32 op-by-op.
__global__ void decode_kernel(const float* __restrict__ obj,
                              const float4* __restrict__ deltas,
                              const float4* __restrict__ anchors,
                              float* __restrict__ score, u32* __restrict__ desc,
                              float4* __restrict__ boxes,
                              u32* __restrict__ blockcnt, u32* __restrict__ blockval) {
    int gid = blockIdx.x * blockDim.x + threadIdx.x;   // grid exact: 3600*256
    float4 a = anchors[gid];
    float4 d = deltas[gid];
    float o = obj[gid];
    float w = __fsub_rn(a.z, a.x), h = __fsub_rn(a.w, a.y);
    float cx = __fadd_rn(a.x, __fmul_rn(0.5f, w));
    float cy = __fadd_rn(a.y, __fmul_rn(0.5f, h));
    float px = __fadd_rn(__fmul_rn(d.x, w), cx);
    float py = __fadd_rn(__fmul_rn(d.y, h), cy);
    float pw = __fmul_rn(expf(fminf(d.z, 4.0f)), w);
    float ph = __fmul_rn(expf(fminf(d.w, 4.0f)), h);
    float x1 = __fsub_rn(px, __fmul_rn(0.5f, pw));
    float y1 = __fsub_rn(py, __fmul_rn(0.5f, ph));
    float x2 = __fadd_rn(px, __fmul_rn(0.5f, pw));
    float y2 = __fadd_rn(py, __fmul_rn(0.5f, ph));
    x1 = fminf(fmaxf(x1, 0.0f), IMGW); x2 = fminf(fmaxf(x2, 0.0f), IMGW);
    y1 = fminf(fmaxf(y1, 0.0f), IMGH); y2 = fminf(fmaxf(y2, 0.0f), IMGH);
    bool valid = (__fsub_rn(x2, x1) >= 1.0f) && (__fsub_rn(y2, y1) >= 1.0f);
    float s = __fdiv_rn(1.0f, __fadd_rn(1.0f, expf(-o)));  // matches np sigmoid branch
    boxes[gid] = make_float4(x1, y1, x2, y2);
    score[gid] = s;
    u32 dsc = valid ? (0x7FFFFFFFu - __float_as_uint(s)) : 0xFFFFFFFFu;
    desc[gid] = dsc;
    bool pass = dsc <= DSC_TH;
    u64 bp = __ballot(pass);
    u64 bv = __ballot(valid);
    __shared__ u32 wcnt[4], wval[4];
    int wid = threadIdx.x >> 6;
    if ((threadIdx.x & 63) == 0) { wcnt[wid] = (u32)__popcll(bp); wval[wid] = (u32)__popcll(bv); }
    __syncthreads();
    if (threadIdx.x == 0) {
        blockcnt[blockIdx.x] = wcnt[0] + wcnt[1] + wcnt[2] + wcnt[3];
        blockval[blockIdx.x] = wval[0] + wval[1] + wval[2] + wval[3];
    }
}

// Per-image exclusive prefix over the 900 block counts (one block per image).
__global__ void scan_kernel(const u32* __restrict__ blockcnt, const u32* __restrict__ blockval,
                            u32* __restrict__ blockoff, u32* __restrict__ selcnt,
                            u32* __restrict__ totval) {
    int img = blockIdx.x, t = threadIdx.x;   // 256 threads
    const u32* BC = blockcnt + img * NBLK;
    u32* BO = blockoff + img * NBLK;
    __shared__ u32 part[256], excl[256], tot;
    int i0 = t * 4;                           // 4*256 = 1024 >= 900
    u32 c[4], s = 0;
    for (int k = 0; k < 4; k++) { int i = i0 + k; c[k] = (i < NBLK) ? BC[i] : 0u; s += c[k]; }
    part[t] = s;
    __syncthreads();
    if (t == 0) {
        u32 run = 0;
        for (int k = 0; k < 256; k++) { excl[k] = run; run += part[k]; }
        tot = run;
    }
    __syncthreads();
    u32 run = excl[t];
    for (int k = 0; k < 4; k++) { int i = i0 + k; if (i < NBLK) BO[i] = run; run += c[k]; }
    if (t == 0) selcnt[img] = tot;
    __syncthreads();
    u32 v = 0;
    for (int k = 0; k < 4; k++) { int i = i0 + k; if (i < NBLK) v += blockval[img * NBLK + i]; }
    part[t] = v;
    __syncthreads();
    if (t == 0) {
        u32 r = 0;
        for (int k = 0; k < 256; k++) r += part[k];
        totval[img] = r;
    }
}

// Deterministic scatter: position = block offset + intra-block ballot prefix. No atomics.
__global__ void scatter_kernel(const u32* __restrict__ desc, const u32* __restrict__ blockoff,
                               u64* __restrict__ selkey) {
    int blk = blockIdx.x, tid = threadIdx.x;
    int gid = blk * 256 + tid;
    int img = blk / NBLK;
    u32 d = desc[gid];
    bool pass = d <= DSC_TH;
    u64 bal = __ballot(pass);
    int lane = tid & 63, wid = tid >> 6;
    __shared__ u32 woff[4];
    if (lane == 0) woff[wid] = (u32)__popcll(bal);
    __syncthreads();
    u32 wbase = 0;
    for (int w = 0; w < wid; w++) wbase += woff[w];
    if (pass) {
        u32 pos = blockoff[blk] + wbase + (u32)__popcll(bal & ((1ull << lane) - 1ull));
        if (pos < SELCAP)
            selkey[(size_t)img * SELCAP + pos] = ((u64)d << 32) | (u32)(gid - img * NANCH);
    }
}

// Enumeration (rank-count) sort of selected items. Keys are unique ((key<<32)|idx),
// so rank is a perfect permutation. Scatter gathers box/score/area into sorted arrays.
__global__ void ranksort_kernel(const u64* __restrict__ selkey, const u32* __restrict__ selcnt,
                                const float4* __restrict__ boxes, const float* __restrict__ score,
                                float4* __restrict__ sbox, float* __restrict__ sscore,
                                float* __restrict__ sarea) {
    int img = blockIdx.y;
    int C = min((int)selcnt[img], SELCAP);
    if ((int)(blockIdx.x * 256) >= C) return;
    int i = blockIdx.x * 256 + threadIdx.x;
    const u64* K = selkey + (size_t)img * SELCAP;
    __shared__ u64 tile[1024];
    bool act = i < C;
    u64 my = act ? K[i] : ~0ull;
    u32 rank = 0;
    for (int t0 = 0; t0 < C; t0 += 1024) {
        int cnt = min(1024, C - t0);
        __syncthreads();
        for (int j = threadIdx.x; j < cnt; j += 256) tile[j] = K[t0 + j];
        __syncthreads();
        for (int j = 0; j < cnt; j++) rank += (tile[j] < my) ? 1u : 0u;
    }
    if (act) {
        int ai = (int)(my & 0xFFFFFFFFu);
        int g = img * NANCH + ai;
        float4 bx = boxes[g];
        size_t o = (size_t)img * SELCAP + rank;
        sbox[o] = bx;
        sscore[o] = score[g];
        sarea[o] = __fmul_rn(fmaxf(__fsub_rn(bx.z, bx.x), 0.0f),
                             fmaxf(__fsub_rn(bx.w, bx.y), 0.0f));
    }
}

// Pairwise IOU>0.5 bitmask over the first min(C,CPROC) sorted candidates.
// Row i, word w: bits for columns j in [w*64, w*64+64). Formula replicates reference f32 ops.
__global__ void mask_kernel(const float4* __restrict__ sbox, const float* __restrict__ sarea,
                            const u32* __restrict__ selcnt, u64* __restrict__ mask) {
    int img = blockIdx.z;
    int C = min((int)selcnt[img], SELCAP);
    int Ce = min(C, CPROC);
    if ((int)(blockIdx.x * 256) >= Ce) return;
    int jtmax = (Ce + 63) >> 6;
    int jt0 = blockIdx.y * 8, jt1 = min(jt0 + 8, jtmax);
    if (jt0 >= jtmax) return;
    int i = blockIdx.x * 256 + threadIdx.x;
    const float4* SB = sbox + (size_t)img * SELCAP;
    const float* SA = sarea + (size_t)img * SELCAP;
    __shared__ float jx1[64], jy1[64], jx2[64], jy2[64], jar[64];
    bool act = i < Ce;
    float4 bi = make_float4(0, 0, 0, 0);
    float ai_ = 0.0f;
    if (act) { bi = SB[i]; ai_ = SA[i]; }
    u64* Mrow = mask + ((size_t)img * CPROC + (size_t)i) * 64;
    for (int jt = jt0; jt < jt1; jt++) {
        int jbase = jt << 6;
        int jcnt = min(64, Ce - jbase);
        __syncthreads();
        if (threadIdx.x < 64) {
            int l = threadIdx.x;
            if (l < jcnt) {
                float4 b = SB[jbase + l];
                jx1[l] = b.x; jy1[l] = b.y; jx2[l] = b.z; jy2[l] = b.w;
                jar[l] = SA[jbase + l];
            } else {
                jx1[l] = 0; jy1[l] = 0; jx2[l] = 0; jy2[l] = 0; jar[l] = 0;
            }
        }
        __syncthreads();
        if (act) {
            u64 bits = 0;
            for (int jl = 0; jl < jcnt; jl++) {
                float ix1 = fmaxf(bi.x, jx1[jl]);
                float iy1 = fmaxf(bi.y, jy1[jl]);
                float ix2 = fminf(bi.z, jx2[jl]);
                float iy2 = fminf(bi.w, jy2[jl]);
                float inter = __fmul_rn(fmaxf(__fsub_rn(ix2, ix1), 0.0f),
                                        fmaxf(__fsub_rn(iy2, iy1), 0.0f));
                float den = __fadd_rn(__fsub_rn(__fadd_rn(ai_, jar[jl]), inter), 1e-9f);
                if (__fdiv_rn(inter, den) > 0.5f) bits |= (1ull << jl);
            }
            Mrow[jt] = bits;
        }
    }
}

// Sweep, v3: 256 threads (4 waves) per image.
// - Accept-resolve per 64-block via WAVE-PARALLEL FIXPOINT A <- A0 & ~supp(A)
//   (forward-only suppression DAG => unique fixpoint == greedy; converges in
//   <=64 iters, typically 2-3 since suppression is rare). Replaces R3's ~59
//   dependent per-bit shfls (~7k cy/block).
// - Suppression-row OR: each thread UNCONDITIONALLY preloads 16 row-words
//   (wave w owns rows == w mod 4, lane l owns word l) at block start — 16
//   independent loads whose latency hides behind wave-0's resolve — then a
//   predicated OR after the accept mask broadcast. Per-wave partial sup in
//   registers; handed to wave 0 via 2KB LDS once per block.
__global__ void sweep_kernel(const float4* __restrict__ sbox, const float* __restrict__ sscore,
                             const float* __restrict__ sarea, const u32* __restrict__ selcnt,
                             const u32* __restrict__ totval, const u64* __restrict__ mask,
                             const u64* __restrict__ selkey, const u32* __restrict__ descarr,
                             const float4* __restrict__ boxes, const float* __restrict__ scorearr,
                             float* __restrict__ out) {
    int img = blockIdx.x;
    int tid = threadIdx.x, lane = tid & 63, wv = tid >> 6;   // 256 threads = 4 waves
    int C = min((int)selcnt[img], SELCAP);
    int Ce = min(C, CPROC);
    const float4* SB = sbox + (size_t)img * SELCAP;
    const float* SS = sscore + (size_t)img * SELCAP;
    const float* SA = sarea + (size_t)img * SELCAP;
    const u64* M = mask + (size_t)img * CPROC * 64;
    const u64* K = selkey + (size_t)img * SELCAP;
    __shared__ float ax1[MAXD], ay1[MAXD], ax2[MAXD], ay2[MAXD], aar[MAXD];
    __shared__ u64 lds_sup4[4][64];
    __shared__ u64 lds_newm;
    __shared__ int lds_na;
    __shared__ u64 red64[4];
    __shared__ int redi[4];
    float* ob = out + (size_t)img * MAXD * 4;
    float* os = out + (size_t)BATCH * MAXD * 4 + (size_t)img * MAXD;
    float* ov = out + (size_t)BATCH * MAXD * 5 + (size_t)img * MAXD;
    lds_sup4[wv][lane] = 0;
    __syncthreads();
    u64 psup = 0;          // this wave's partial suppression word `lane`
    int acc = 0;
    int nblk = (Ce + 63) >> 6;
    for (int ib = 0; ib < nblk && acc < MAXD; ib++) {
        int base = ib << 6;
        int bcount = min(64, Ce - base);
        // issue 16 independent row loads (rows base+wv+4k, word `lane`)
        u64 vals[16];
        #pragma unroll
        for (int k = 0; k < 16; k++) {
            int r = wv + 4 * k;
            vals[k] = (r < bcount) ? M[(size_t)(base + r) * 64 + lane] : 0ull;
        }
        if (wv == 0) {
            u64 tile = (lane < bcount) ? M[(size_t)(base + lane) * 64 + ib] : 0ull;
            u64 ext = lds_sup4[0][ib] | lds_sup4[1][ib] | lds_sup4[2][ib] | lds_sup4[3][ib];
            u64 range = (bcount == 64) ? ~0ull : ((1ull << bcount) - 1ull);
            u64 fut = (lane == 63) ? 0ull : (~0ull << (lane + 1));
            u64 A0 = ~ext & range;
            u64 A = A0;
            for (int it = 0; it < 64; it++) {
                u64 S = ((A >> lane) & 1ull) ? (tile & fut) : 0ull;
                #pragma unroll
                for (int off = 1; off < 64; off <<= 1) S |= __shfl_xor(S, off);
                u64 An = A0 & ~S;
                if (An == A) break;     // uniform: fixpoint == greedy
                A = An;
            }
            int cnt = __popcll(A);
            int keep = MAXD - acc;
            while (cnt > keep) {        // cap at 1000: keep first `keep` bits (exact)
                A &= ~(1ull << (63 - __builtin_clzll(A)));
                cnt--;
            }
            if (lane == 0) { lds_newm = A; lds_na = cnt; }
        }
        __syncthreads();
        u64 newm = lds_newm;
        int na = lds_na;
        // predicated OR of accepted rows into the register partial
        #pragma unroll
        for (int k = 0; k < 16; k++) {
            int r = wv + 4 * k;
            psup |= ((newm >> r) & 1ull) ? vals[k] : 0ull;
        }
        // lane-parallel outputs: thread t takes the t-th set bit of newm
        if (tid < na) {
            u64 sel = newm;
            for (int k = 0; k < tid; k++) sel &= sel - 1;
            int i = base + (int)__builtin_ctzll(sel);
            int o = acc + tid;
            float4 bx = SB[i];
            ((float4*)ob)[o] = bx;
            os[o] = SS[i]; ov[o] = 1.0f;
            ax1[o] = bx.x; ay1[o] = bx.y; ax2[o] = bx.z; ay2[o] = bx.w;
            aar[o] = SA[i];
        }
        acc += na;
        lds_sup4[wv][lane] = psup;
        __syncthreads();
    }
    // Continuation A (exact, ~never taken): selected candidates beyond the mask window.
    for (int i = Ce; i < C && acc < MAXD; i++) {
        float4 bx = SB[i];
        float ar = SA[i];
        bool hit = false;
        for (int k = tid; k < acc; k += 256) {
            float ix1 = fmaxf(bx.x, ax1[k]);
            float iy1 = fmaxf(bx.y, ay1[k]);
            float ix2 = fminf(bx.z, ax2[k]);
            float iy2 = fminf(bx.w, ay2[k]);
            float inter = __fmul_rn(fmaxf(__fsub_rn(ix2, ix1), 0.0f),
                                    fmaxf(__fsub_rn(iy2, iy1), 0.0f));
            float den = __fadd_rn(__fsub_rn(__fadd_rn(aar[k], ar), inter), 1e-9f);
            if (__fdiv_rn(inter, den) > 0.5f) { hit = true; break; }
        }
        u64 bal = __ballot(hit);
        if (lane == 0) redi[wv] = (bal != 0ull) ? 1 : 0;
        __syncthreads();
        bool any = (redi[0] | redi[1] | redi[2] | redi[3]) != 0;
        __syncthreads();
        if (!any) {
            if (tid == 0) {
                ob[acc * 4 + 0] = bx.x; ob[acc * 4 + 1] = bx.y;
                ob[acc * 4 + 2] = bx.z; ob[acc * 4 + 3] = bx.w;
                os[acc] = SS[i]; ov[acc] = 1.0f;
                ax1[acc] = bx.x; ay1[acc] = bx.y; ax2[acc] = bx.z; ay2[acc] = bx.w;
                aar[acc] = ar;
            }
            __syncthreads();
            acc++;
        }
    }
    // Continuation B (exact deep fallback, ~never taken): valid candidates beyond selection.
    u32 tv = totval[img];
    if (acc < MAXD && (u32)C < tv && (u32)C == selcnt[img]) {
        u64 lk = 0;
        for (int j = tid; j < C; j += 256) lk = max(lk, K[j]);
        for (int off = 32; off; off >>= 1) { u64 o = __shfl_down(lk, off); lk = max(lk, o); }
        if (lane == 0) red64[wv] = lk;
        __syncthreads();
        lk = max(max(red64[0], red64[1]), max(red64[2], red64[3]));
        __syncthreads();
        while (acc < MAXD) {
            u64 best = ~0ull;
            for (int j = tid; j < NANCH; j += 256) {
                u32 d = descarr[(size_t)img * NANCH + j];
                if (d != 0xFFFFFFFFu) {
                    u64 kk = ((u64)d << 32) | (u32)j;
                    if (kk > lk && kk < best) best = kk;
                }
            }
            for (int off = 32; off; off >>= 1) { u64 o = __shfl_down(best, off); best = min(best, o); }
            if (lane == 0) red64[wv] = best;
            __syncthreads();
            best = min(min(red64[0], red64[1]), min(red64[2], red64[3]));
            __syncthreads();
            if (best == ~0ull) break;
            lk = best;
            int ai = (int)(best & 0xFFFFFFFFu);
            int g = img * NANCH + ai;
            float4 bx = boxes[g];
            float ar = __fmul_rn(fmaxf(__fsub_rn(bx.z, bx.x), 0.0f),
                                 fmaxf(__fsub_rn(bx.w, bx.y), 0.0f));
            bool hit = false;
            for (int k = tid; k < acc; k += 256) {
                float ix1 = fmaxf(bx.x, ax1[k]);
                float iy1 = fmaxf(bx.y, ay1[k]);
                float ix2 = fminf(bx.z, ax2[k]);
                float iy2 = fminf(bx.w, ay2[k]);
                float inter = __fmul_rn(fmaxf(__fsub_rn(ix2, ix1), 0.0f),
                                        fmaxf(__fsub_rn(iy2, iy1), 0.0f));
                float den = __fadd_rn(__fsub_rn(__fadd_rn(aar[k], ar), inter), 1e-9f);
                if (__fdiv_rn(inter, den) > 0.5f) { hit = true; break; }
            }
            u64 bal = __ballot(hit);
            if (lane == 0) redi[wv] = (bal != 0ull) ? 1 : 0;
            __syncthreads();
            bool any = (redi[0] | redi[1] | redi[2] | redi[3]) != 0;
            __syncthreads();
            if (!any) {
                if (tid == 0) {
                    ob[acc * 4 + 0] = bx.x; ob[acc * 4 + 1] = bx.y;
                    ob[acc * 4 + 2] = bx.z; ob[acc * 4 + 3] = bx.w;
                    os[acc] = scorearr[g]; ov[acc] = 1.0f;
                    ax1[acc] = bx.x; ay1[acc] = bx.y; ax2[acc] = bx.z; ay2[acc] = bx.w;
                    aar[acc] = ar;
                }
                __syncthreads();
                acc++;
            }
        }
    }
}

extern "C" void kernel_launch(void* const* d_in, const int* in_sizes, int n_in,
                              void* d_out, int out_size, void* d_ws, size_t ws_size,
                              hipStream_t stream) {
    const float* obj = (const float*)d_in[0];
    const float4* deltas = (const float4*)d_in[1];
    const float4* anchors = (const float4*)d_in[2];
    char* ws = (char*)d_ws;
    u32* blockcnt = (u32*)(ws + BLKCNT_OFF);
    u32* blockval = (u32*)(ws + BLKVAL_OFF);
    u32* blockoff = (u32*)(ws + BLKOFF_OFF);
    u32* selcnt = (u32*)(ws + SELCNT_OFF);
    u32* totval = (u32*)(ws + TOTVAL_OFF);
    float* score = (float*)(ws + SCORE_OFF);
    u32* desc = (u32*)(ws + DESC_OFF);
    float4* boxes = (float4*)(ws + BOX_OFF);
    u64* selkey = (u64*)(ws + SELKEY_OFF);
    float4* sbox = (float4*)(ws + SBOX_OFF);
    float* sscore = (float*)(ws + SSCORE_OFF);
    float* sarea = (float*)(ws + SAREA_OFF);
    u64* mask = (u64*)(ws + MASK_OFF);
    float* out = (float*)d_out;

    hipMemsetAsync(d_out, 0, (size_t)out_size * sizeof(float), stream);    // zero-padded outputs

    decode_kernel<<<3600, 256, 0, stream>>>(obj, deltas, anchors, score, desc, boxes,
                                            blockcnt, blockval);
    scan_kernel<<<BATCH, 256, 0, stream>>>(blockcnt, blockval, blockoff, selcnt, totval);
    scatter_kernel<<<3600, 256, 0, stream>>>(desc, blockoff, selkey);
    ranksort_kernel<<<dim3(SELCAP / 256, BATCH), 256, 0, stream>>>(selkey, selcnt, boxes, score,
                                                                   sbox, sscore, sarea);
    mask_kernel<<<dim3(CPROC / 256, 8, BATCH), 256, 0, stream>>>(sbox, sarea, selcnt, mask);
    sweep_kernel<<<BATCH, 256, 0, stream>>>(sbox, sscore, sarea, selcnt, totval, mask,
                                            selkey, desc, boxes, score, out);
}

// Round 5
// 241.040 us; speedup vs baseline: 5.1337x; 1.2960x over previous
//
#include <hip/hip_runtime.h>
#include <stdint.h>

typedef unsigned long long u64;
typedef unsigned int u32;

#define BATCH 4
#define NANCH 230400          // 160*160*9
#define NBLK  900             // blocks of 256 per image (exact)
#define SELCAP 8192           // selection buffer cap per image
#define CPROC 4096            // candidates covered by pairwise bitmask (64 u64 words/row)
#define NJC   8               // j-chunks for rank partials
#define MAXD 1000
#define IMGW 1280.0f
#define IMGH 1280.0f

// Fixed selection threshold: score >= 0.91 (= sigmoid(2.3136), f32 bits 0x3F68F5C3).
// desc key = 0x7FFFFFFF - float_bits(score), so pass <=> desc <= DSC_TH.
// Expected passers/image = 230400 * P(N(0,1)>2.3136) = 2382 +- 49; NMS examines ~1150
// (25 sigma margin). Selection is prefix-closed in key space for ANY threshold, and
// sweep's Continuations A/B are exact fallbacks — correctness never depends on this
// constant, only speed. [R4: was sigmoid(2.0) -> C=5242; cut to shrink O(C^2) stages.]
#define DSC_TH 0x40970A3Cu

// ---- workspace layout (bytes). Total 32,669,696 (== R4's proven footprint) ----
#define BLKCNT_OFF 0                                   // u32 [BATCH*NBLK]
#define BLKVAL_OFF (BLKCNT_OFF + BATCH*NBLK*4)
#define BLKOFF_OFF (BLKVAL_OFF + BATCH*NBLK*4)
#define SELCNT_OFF (BLKOFF_OFF + BATCH*NBLK*4)         // u32 [BATCH]
#define TOTVAL_OFF (SELCNT_OFF + BATCH*4)
#define SCORE_OFF  65536                               // f32 [BATCH*NANCH]
#define DESC_OFF   (SCORE_OFF + BATCH*NANCH*4)         // u32 [BATCH*NANCH]
#define BOX_OFF    (DESC_OFF + BATCH*NANCH*4)          // float4 [BATCH*NANCH]
#define SELKEY_OFF (BOX_OFF + (size_t)BATCH*NANCH*16)  // u64 [BATCH*SELCAP]
#define SBOX_OFF   (SELKEY_OFF + (size_t)BATCH*SELCAP*8)
#define SSCORE_OFF (SBOX_OFF + (size_t)BATCH*SELCAP*16)
#define SAREA_OFF  (SSCORE_OFF + (size_t)BATCH*SELCAP*4)
#define PART_OFF   (SAREA_OFF + (size_t)BATCH*SELCAP*4)   // u32 [BATCH*SELCAP*NJC]
#define MASK_OFF   (PART_OFF + (size_t)BATCH*SELCAP*NJC*4) // u64 [BATCH*CPROC*64]

// Decode: sigmoid score, box decode+clip, validity, sortable key, per-block
// pass/valid counts via ballot (no atomics). All rounding-sensitive ops via
// __f*_rn to match numpy f32 op-by-op.
__global__ void decode_kernel(const float* __restrict__ obj,
                              const float4* __restrict__ deltas,
                              const float4* __restrict__ anchors,
                              float* __restrict__ score, u32* __restrict__ desc,
                              float4* __restrict__ boxes,
                              u32* __restrict__ blockcnt, u32* __restrict__ blockval) {
    int gid = blockIdx.x * blockDim.x + threadIdx.x;   // grid exact: 3600*256
    float4 a = anchors[gid];
    float4 d = deltas[gid];
    float o = obj[gid];
    float w = __fsub_rn(a.z, a.x), h = __fsub_rn(a.w, a.y);
    float cx = __fadd_rn(a.x, __fmul_rn(0.5f, w));
    float cy = __fadd_rn(a.y, __fmul_rn(0.5f, h));
    float px = __fadd_rn(__fmul_rn(d.x, w), cx);
    float py = __fadd_rn(__fmul_rn(d.y, h), cy);
    float pw = __fmul_rn(expf(fminf(d.z, 4.0f)), w);
    float ph = __fmul_rn(expf(fminf(d.w, 4.0f)), h);
    float x1 = __fsub_rn(px, __fmul_rn(0.5f, pw));
    float y1 = __fsub_rn(py, __fmul_rn(0.5f, ph));
    float x2 = __fadd_rn(px, __fmul_rn(0.5f, pw));
    float y2 = __fadd_rn(py, __fmul_rn(0.5f, ph));
    x1 = fminf(fmaxf(x1, 0.0f), IMGW); x2 = fminf(fmaxf(x2, 0.0f), IMGW);
    y1 = fminf(fmaxf(y1, 0.0f), IMGH); y2 = fminf(fmaxf(y2, 0.0f), IMGH);
    bool valid = (__fsub_rn(x2, x1) >= 1.0f) && (__fsub_rn(y2, y1) >= 1.0f);
    float s = __fdiv_rn(1.0f, __fadd_rn(1.0f, expf(-o)));  // matches np sigmoid branch
    boxes[gid] = make_float4(x1, y1, x2, y2);
    score[gid] = s;
    u32 dsc = valid ? (0x7FFFFFFFu - __float_as_uint(s)) : 0xFFFFFFFFu;
    desc[gid] = dsc;
    bool pass = dsc <= DSC_TH;
    u64 bp = __ballot(pass);
    u64 bv = __ballot(valid);
    __shared__ u32 wcnt[4], wval[4];
    int wid = threadIdx.x >> 6;
    if ((threadIdx.x & 63) == 0) { wcnt[wid] = (u32)__popcll(bp); wval[wid] = (u32)__popcll(bv); }
    __syncthreads();
    if (threadIdx.x == 0) {
        blockcnt[blockIdx.x] = wcnt[0] + wcnt[1] + wcnt[2] + wcnt[3];
        blockval[blockIdx.x] = wval[0] + wval[1] + wval[2] + wval[3];
    }
}

// Per-image exclusive prefix over the 900 block counts (one block per image).
__global__ void scan_kernel(const u32* __restrict__ blockcnt, const u32* __restrict__ blockval,
                            u32* __restrict__ blockoff, u32* __restrict__ selcnt,
                            u32* __restrict__ totval) {
    int img = blockIdx.x, t = threadIdx.x;   // 256 threads
    const u32* BC = blockcnt + img * NBLK;
    u32* BO = blockoff + img * NBLK;
    __shared__ u32 part[256], excl[256], tot;
    int i0 = t * 4;                           // 4*256 = 1024 >= 900
    u32 c[4], s = 0;
    for (int k = 0; k < 4; k++) { int i = i0 + k; c[k] = (i < NBLK) ? BC[i] : 0u; s += c[k]; }
    part[t] = s;
    __syncthreads();
    if (t == 0) {
        u32 run = 0;
        for (int k = 0; k < 256; k++) { excl[k] = run; run += part[k]; }
        tot = run;
    }
    __syncthreads();
    u32 run = excl[t];
    for (int k = 0; k < 4; k++) { int i = i0 + k; if (i < NBLK) BO[i] = run; run += c[k]; }
    if (t == 0) selcnt[img] = tot;
    __syncthreads();
    u32 v = 0;
    for (int k = 0; k < 4; k++) { int i = i0 + k; if (i < NBLK) v += blockval[img * NBLK + i]; }
    part[t] = v;
    __syncthreads();
    if (t == 0) {
        u32 r = 0;
        for (int k = 0; k < 256; k++) r += part[k];
        totval[img] = r;
    }
}

// Deterministic scatter: position = block offset + intra-block ballot prefix. No atomics.
__global__ void scatter_kernel(const u32* __restrict__ desc, const u32* __restrict__ blockoff,
                               u64* __restrict__ selkey) {
    int blk = blockIdx.x, tid = threadIdx.x;
    int gid = blk * 256 + tid;
    int img = blk / NBLK;
    u32 d = desc[gid];
    bool pass = d <= DSC_TH;
    u64 bal = __ballot(pass);
    int lane = tid & 63, wid = tid >> 6;
    __shared__ u32 woff[4];
    if (lane == 0) woff[wid] = (u32)__popcll(bal);
    __syncthreads();
    u32 wbase = 0;
    for (int w = 0; w < wid; w++) wbase += woff[w];
    if (pass) {
        u32 pos = blockoff[blk] + wbase + (u32)__popcll(bal & ((1ull << lane) - 1ull));
        if (pos < SELCAP)
            selkey[(size_t)img * SELCAP + pos] = ((u64)d << 32) | (u32)(gid - img * NANCH);
    }
}

// Rank pass 1: partial rank of item i against j-chunk jc (C/NJC keys), 8-wide
// unrolled LDS compares. [R4: single-kernel version was a C=5242-long serial
// latency-bound loop at 3.7% occupancy -> 79 us. j-split x8 + unroll x8.]
__global__ void rankpart_kernel(const u64* __restrict__ selkey, const u32* __restrict__ selcnt,
                                u32* __restrict__ partial) {
    int img = blockIdx.z;
    int C = min((int)selcnt[img], SELCAP);
    if ((int)(blockIdx.x * 256) >= C) return;
    int tid = threadIdx.x;
    int i = blockIdx.x * 256 + tid;
    int jc = blockIdx.y;
    int chunk = (C + NJC - 1) / NJC;
    int j0 = jc * chunk, j1 = min(j0 + chunk, C);
    const u64* K = selkey + (size_t)img * SELCAP;
    __shared__ u64 tile[1024];
    bool act = i < C;
    u64 my = act ? K[i] : ~0ull;
    u32 r = 0;
    for (int t0 = j0; t0 < j1; t0 += 1024) {
        int cnt = min(1024, j1 - t0);
        __syncthreads();
        for (int j = tid; j < cnt; j += 256) tile[j] = K[t0 + j];
        __syncthreads();
        int j = 0;
        for (; j + 8 <= cnt; j += 8) {
            u64 a0 = tile[j], a1 = tile[j+1], a2 = tile[j+2], a3 = tile[j+3];
            u64 a4 = tile[j+4], a5 = tile[j+5], a6 = tile[j+6], a7 = tile[j+7];
            r += (a0 < my) + (a1 < my) + (a2 < my) + (a3 < my)
               + (a4 < my) + (a5 < my) + (a6 < my) + (a7 < my);
        }
        for (; j < cnt; j++) r += (tile[j] < my) ? 1u : 0u;
    }
    if (act) partial[((size_t)img * SELCAP + i) * NJC + jc] = r;
}

// Rank pass 2: sum NJC partials -> final rank (perfect permutation, keys unique),
// gather box/score/area into sorted arrays.
__global__ void rankgather_kernel(const u64* __restrict__ selkey, const u32* __restrict__ selcnt,
                                  const u32* __restrict__ partial,
                                  const float4* __restrict__ boxes, const float* __restrict__ score,
                                  float4* __restrict__ sbox, float* __restrict__ sscore,
                                  float* __restrict__ sarea) {
    int img = blockIdx.y;
    int C = min((int)selcnt[img], SELCAP);
    if ((int)(blockIdx.x * 256) >= C) return;
    int i = blockIdx.x * 256 + threadIdx.x;
    if (i >= C) return;
    const u32* P = partial + ((size_t)img * SELCAP + i) * NJC;
    u32 rank = 0;
    #pragma unroll
    for (int k = 0; k < NJC; k++) rank += P[k];
    u64 my = selkey[(size_t)img * SELCAP + i];
    int ai = (int)(my & 0xFFFFFFFFu);
    int g = img * NANCH + ai;
    float4 bx = boxes[g];
    size_t o = (size_t)img * SELCAP + rank;
    sbox[o] = bx;
    sscore[o] = score[g];
    sarea[o] = __fmul_rn(fmaxf(__fsub_rn(bx.z, bx.x), 0.0f),
                         fmaxf(__fsub_rn(bx.w, bx.y), 0.0f));
}

// Pairwise IOU>0.5 bitmask over the first min(C,CPROC) sorted candidates.
// Row i, word w: bits for columns j in [w*64, w*64+64). Formula replicates reference f32 ops.
__global__ void mask_kernel(const float4* __restrict__ sbox, const float* __restrict__ sarea,
                            const u32* __restrict__ selcnt, u64* __restrict__ mask) {
    int img = blockIdx.z;
    int C = min((int)selcnt[img], SELCAP);
    int Ce = min(C, CPROC);
    if ((int)(blockIdx.x * 256) >= Ce) return;
    int jtmax = (Ce + 63) >> 6;
    int jt0 = blockIdx.y * 8, jt1 = min(jt0 + 8, jtmax);
    if (jt0 >= jtmax) return;
    int i = blockIdx.x * 256 + threadIdx.x;
    const float4* SB = sbox + (size_t)img * SELCAP;
    const float* SA = sarea + (size_t)img * SELCAP;
    __shared__ float jx1[64], jy1[64], jx2[64], jy2[64], jar[64];
    bool act = i < Ce;
    float4 bi = make_float4(0, 0, 0, 0);
    float ai_ = 0.0f;
    if (act) { bi = SB[i]; ai_ = SA[i]; }
    u64* Mrow = mask + ((size_t)img * CPROC + (size_t)i) * 64;
    for (int jt = jt0; jt < jt1; jt++) {
        int jbase = jt << 6;
        int jcnt = min(64, Ce - jbase);
        __syncthreads();
        if (threadIdx.x < 64) {
            int l = threadIdx.x;
            if (l < jcnt) {
                float4 b = SB[jbase + l];
                jx1[l] = b.x; jy1[l] = b.y; jx2[l] = b.z; jy2[l] = b.w;
                jar[l] = SA[jbase + l];
            } else {
                jx1[l] = 0; jy1[l] = 0; jx2[l] = 0; jy2[l] = 0; jar[l] = 0;
            }
        }
        __syncthreads();
        if (act) {
            u64 bits = 0;
            for (int jl = 0; jl < jcnt; jl++) {
                float ix1 = fmaxf(bi.x, jx1[jl]);
                float iy1 = fmaxf(bi.y, jy1[jl]);
                float ix2 = fminf(bi.z, jx2[jl]);
                float iy2 = fminf(bi.w, jy2[jl]);
                float inter = __fmul_rn(fmaxf(__fsub_rn(ix2, ix1), 0.0f),
                                        fmaxf(__fsub_rn(iy2, iy1), 0.0f));
                float den = __fadd_rn(__fsub_rn(__fadd_rn(ai_, jar[jl]), inter), 1e-9f);
                if (__fdiv_rn(inter, den) > 0.5f) bits |= (1ull << jl);
            }
            Mrow[jt] = bits;
        }
    }
}

// Sweep: 256 threads (4 waves) per image. Wave-parallel fixpoint resolve per
// 64-block; unconditional 16-deep row preloads; predicated OR; lane-parallel
// output writes. See R4 notes.
__global__ void sweep_kernel(const float4* __restrict__ sbox, const float* __restrict__ sscore,
                             const float* __restrict__ sarea, const u32* __restrict__ selcnt,
                             const u32* __restrict__ totval, const u64* __restrict__ mask,
                             const u64* __restrict__ selkey, const u32* __restrict__ descarr,
                             const float4* __restrict__ boxes, const float* __restrict__ scorearr,
                             float* __restrict__ out) {
    int img = blockIdx.x;
    int tid = threadIdx.x, lane = tid & 63, wv = tid >> 6;   // 256 threads = 4 waves
    int C = min((int)selcnt[img], SELCAP);
    int Ce = min(C, CPROC);
    const float4* SB = sbox + (size_t)img * SELCAP;
    const float* SS = sscore + (size_t)img * SELCAP;
    const float* SA = sarea + (size_t)img * SELCAP;
    const u64* M = mask + (size_t)img * CPROC * 64;
    const u64* K = selkey + (size_t)img * SELCAP;
    __shared__ float ax1[MAXD], ay1[MAXD], ax2[MAXD], ay2[MAXD], aar[MAXD];
    __shared__ u64 lds_sup4[4][64];
    __shared__ u64 lds_newm;
    __shared__ int lds_na;
    __shared__ u64 red64[4];
    __shared__ int redi[4];
    float* ob = out + (size_t)img * MAXD * 4;
    float* os = out + (size_t)BATCH * MAXD * 4 + (size_t)img * MAXD;
    float* ov = out + (size_t)BATCH * MAXD * 5 + (size_t)img * MAXD;
    lds_sup4[wv][lane] = 0;
    __syncthreads();
    u64 psup = 0;          // this wave's partial suppression word `lane`
    int acc = 0;
    int nblk = (Ce + 63) >> 6;
    for (int ib = 0; ib < nblk && acc < MAXD; ib++) {
        int base = ib << 6;
        int bcount = min(64, Ce - base);
        // issue 16 independent row loads (rows base+wv+4k, word `lane`)
        u64 vals[16];
        #pragma unroll
        for (int k = 0; k < 16; k++) {
            int r = wv + 4 * k;
            vals[k] = (r < bcount) ? M[(size_t)(base + r) * 64 + lane] : 0ull;
        }
        if (wv == 0) {
            u64 tile = (lane < bcount) ? M[(size_t)(base + lane) * 64 + ib] : 0ull;
            u64 ext = lds_sup4[0][ib] | lds_sup4[1][ib] | lds_sup4[2][ib] | lds_sup4[3][ib];
            u64 range = (bcount == 64) ? ~0ull : ((1ull << bcount) - 1ull);
            u64 fut = (lane == 63) ? 0ull : (~0ull << (lane + 1));
            u64 A0 = ~ext & range;
            u64 A = A0;
            for (int it = 0; it < 64; it++) {
                u64 S = ((A >> lane) & 1ull) ? (tile & fut) : 0ull;
                #pragma unroll
                for (int off = 1; off < 64; off <<= 1) S |= __shfl_xor(S, off);
                u64 An = A0 & ~S;
                if (An == A) break;     // uniform: fixpoint == greedy
                A = An;
            }
            int cnt = __popcll(A);
            int keep = MAXD - acc;
            while (cnt > keep) {        // cap at 1000: keep first `keep` bits (exact)
                A &= ~(1ull << (63 - __builtin_clzll(A)));
                cnt--;
            }
            if (lane == 0) { lds_newm = A; lds_na = cnt; }
        }
        __syncthreads();
        u64 newm = lds_newm;
        int na = lds_na;
        // predicated OR of accepted rows into the register partial
        #pragma unroll
        for (int k = 0; k < 16; k++) {
            int r = wv + 4 * k;
            psup |= ((newm >> r) & 1ull) ? vals[k] : 0ull;
        }
        // lane-parallel outputs: thread t takes the t-th set bit of newm
        if (tid < na) {
            u64 sel = newm;
            for (int k = 0; k < tid; k++) sel &= sel - 1;
            int i = base + (int)__builtin_ctzll(sel);
            int o = acc + tid;
            float4 bx = SB[i];
            ((float4*)ob)[o] = bx;
            os[o] = SS[i]; ov[o] = 1.0f;
            ax1[o] = bx.x; ay1[o] = bx.y; ax2[o] = bx.z; ay2[o] = bx.w;
            aar[o] = SA[i];
        }
        acc += na;
        lds_sup4[wv][lane] = psup;
        __syncthreads();
    }
    // Continuation A (exact, ~never taken): selected candidates beyond the mask window.
    for (int i = Ce; i < C && acc < MAXD; i++) {
        float4 bx = SB[i];
        float ar = SA[i];
        bool hit = false;
        for (int k = tid; k < acc; k += 256) {
            float ix1 = fmaxf(bx.x, ax1[k]);
            float iy1 = fmaxf(bx.y, ay1[k]);
            float ix2 = fminf(bx.z, ax2[k]);
            float iy2 = fminf(bx.w, ay2[k]);
            float inter = __fmul_rn(fmaxf(__fsub_rn(ix2, ix1), 0.0f),
                                    fmaxf(__fsub_rn(iy2, iy1), 0.0f));
            float den = __fadd_rn(__fsub_rn(__fadd_rn(aar[k], ar), inter), 1e-9f);
            if (__fdiv_rn(inter, den) > 0.5f) { hit = true; break; }
        }
        u64 bal = __ballot(hit);
        if (lane == 0) redi[wv] = (bal != 0ull) ? 1 : 0;
        __syncthreads();
        bool any = (redi[0] | redi[1] | redi[2] | redi[3]) != 0;
        __syncthreads();
        if (!any) {
            if (tid == 0) {
                ob[acc * 4 + 0] = bx.x; ob[acc * 4 + 1] = bx.y;
                ob[acc * 4 + 2] = bx.z; ob[acc * 4 + 3] = bx.w;
                os[acc] = SS[i]; ov[acc] = 1.0f;
                ax1[acc] = bx.x; ay1[acc] = bx.y; ax2[acc] = bx.z; ay2[acc] = bx.w;
                aar[acc] = ar;
            }
            __syncthreads();
            acc++;
        }
    }
    // Continuation B (exact deep fallback, ~never taken): valid candidates beyond selection.
    u32 tv = totval[img];
    if (acc < MAXD && (u32)C < tv && (u32)C == selcnt[img]) {
        u64 lk = 0;
        for (int j = tid; j < C; j += 256) lk = max(lk, K[j]);
        for (int off = 32; off; off >>= 1) { u64 o = __shfl_down(lk, off); lk = max(lk, o); }
        if (lane == 0) red64[wv] = lk;
        __syncthreads();
        lk = max(max(red64[0], red64[1]), max(red64[2], red64[3]));
        __syncthreads();
        while (acc < MAXD) {
            u64 best = ~0ull;
            for (int j = tid; j < NANCH; j += 256) {
                u32 d = descarr[(size_t)img * NANCH + j];
                if (d != 0xFFFFFFFFu) {
                    u64 kk = ((u64)d << 32) | (u32)j;
                    if (kk > lk && kk < best) best = kk;
                }
            }
            for (int off = 32; off; off >>= 1) { u64 o = __shfl_down(best, off); best = min(best, o); }
            if (lane == 0) red64[wv] = best;
            __syncthreads();
            best = min(min(red64[0], red64[1]), min(red64[2], red64[3]));
            __syncthreads();
            if (best == ~0ull) break;
            lk = best;
            int ai = (int)(best & 0xFFFFFFFFu);
            int g = img * NANCH + ai;
            float4 bx = boxes[g];
            float ar = __fmul_rn(fmaxf(__fsub_rn(bx.z, bx.x), 0.0f),
                                 fmaxf(__fsub_rn(bx.w, bx.y), 0.0f));
            bool hit = false;
            for (int k = tid; k < acc; k += 256) {
                float ix1 = fmaxf(bx.x, ax1[k]);
                float iy1 = fmaxf(bx.y, ay1[k]);
                float ix2 = fminf(bx.z, ax2[k]);
                float iy2 = fminf(bx.w, ay2[k]);
                float inter = __fmul_rn(fmaxf(__fsub_rn(ix2, ix1), 0.0f),
                                        fmaxf(__fsub_rn(iy2, iy1), 0.0f));
                float den = __fadd_rn(__fsub_rn(__fadd_rn(aar[k], ar), inter), 1e-9f);
                if (__fdiv_rn(inter, den) > 0.5f) { hit = true; break; }
            }
            u64 bal = __ballot(hit);
            if (lane == 0) redi[wv] = (bal != 0ull) ? 1 : 0;
            __syncthreads();
            bool any = (redi[0] | redi[1] | redi[2] | redi[3]) != 0;
            __syncthreads();
            if (!any) {
                if (tid == 0) {
                    ob[acc * 4 + 0] = bx.x; ob[acc * 4 + 1] = bx.y;
                    ob[acc * 4 + 2] = bx.z; ob[acc * 4 + 3] = bx.w;
                    os[acc] = scorearr[g]; ov[acc] = 1.0f;
                    ax1[acc] = bx.x; ay1[acc] = bx.y; ax2[acc] = bx.z; ay2[acc] = bx.w;
                    aar[acc] = ar;
                }
                __syncthreads();
                acc++;
            }
        }
    }
}

extern "C" void kernel_launch(void* const* d_in, const int* in_sizes, int n_in,
                              void* d_out, int out_size, void* d_ws, size_t ws_size,
                              hipStream_t stream) {
    const float* obj = (const float*)d_in[0];
    const float4* deltas = (const float4*)d_in[1];
    const float4* anchors = (const float4*)d_in[2];
    char* ws = (char*)d_ws;
    u32* blockcnt = (u32*)(ws + BLKCNT_OFF);
    u32* blockval = (u32*)(ws + BLKVAL_OFF);
    u32* blockoff = (u32*)(ws + BLKOFF_OFF);
    u32* selcnt = (u32*)(ws + SELCNT_OFF);
    u32* totval = (u32*)(ws + TOTVAL_OFF);
    float* score = (float*)(ws + SCORE_OFF);
    u32* desc = (u32*)(ws + DESC_OFF);
    float4* boxes = (float4*)(ws + BOX_OFF);
    u64* selkey = (u64*)(ws + SELKEY_OFF);
    float4* sbox = (float4*)(ws + SBOX_OFF);
    float* sscore = (float*)(ws + SSCORE_OFF);
    float* sarea = (float*)(ws + SAREA_OFF);
    u32* partial = (u32*)(ws + PART_OFF);
    u64* mask = (u64*)(ws + MASK_OFF);
    float* out = (float*)d_out;

    hipMemsetAsync(d_out, 0, (size_t)out_size * sizeof(float), stream);    // zero-padded outputs

    decode_kernel<<<3600, 256, 0, stream>>>(obj, deltas, anchors, score, desc, boxes,
                                            blockcnt, blockval);
    scan_kernel<<<BATCH, 256, 0, stream>>>(blockcnt, blockval, blockoff, selcnt, totval);
    scatter_kernel<<<3600, 256, 0, stream>>>(desc, blockoff, selkey);
    rankpart_kernel<<<dim3(SELCAP / 256, NJC, BATCH), 256, 0, stream>>>(selkey, selcnt, partial);
    rankgather_kernel<<<dim3(SELCAP / 256, BATCH), 256, 0, stream>>>(selkey, selcnt, partial,
                                                                     boxes, score,
                                                                     sbox, sscore, sarea);
    mask_kernel<<<dim3(CPROC / 256, 8, BATCH), 256, 0, stream>>>(sbox, sarea, selcnt, mask);
    sweep_kernel<<<BATCH, 256, 0, stream>>>(sbox, sscore, sarea, selcnt, totval, mask,
                                            selkey, desc, boxes, score, out);
}